// Round 6
// baseline (355.634 us; speedup 1.0000x reference)
//
#include <hip/hip_runtime.h>
#include <hip/hip_bf16.h>

#define B_ 2
#define T_ 1024
#define H_ 8
#define D_ 64
#define C_ 512
#define M_ 32768
#define TOPK_ 32
#define NCAND_ 64
#define SCALE_ 0.125f
#define QSCALE_ 360.0f
#define KSCALE_ 24.0f
#define OSCALE_ 20.0f

typedef unsigned short u16;
typedef float    f32x2  __attribute__((ext_vector_type(2)));
typedef float    f32x4  __attribute__((ext_vector_type(4)));
typedef __bf16   bf16x8 __attribute__((ext_vector_type(8)));
typedef u16      u16x4  __attribute__((ext_vector_type(4)));
typedef int      i32x4  __attribute__((ext_vector_type(4)));
typedef unsigned char u8x4 __attribute__((ext_vector_type(4)));

__device__ __forceinline__ u16 f2bf(float f) {
  __hip_bfloat16 b = __float2bfloat16(f);
  u16 u; __builtin_memcpy(&u, &b, 2); return u;
}

__device__ __forceinline__ unsigned char q8(float v, float scale) {
  int iv = (int)rintf(v * scale);
  iv = iv > 127 ? 127 : (iv < -127 ? -127 : iv);
  return (unsigned char)(signed char)iv;
}

__device__ __forceinline__ void gl_lds16(const void* g, void* l) {
  __builtin_amdgcn_global_load_lds(
      (const __attribute__((address_space(1))) void*)g,
      (__attribute__((address_space(3))) void*)l, 16, 0, 0);
}

// ---------------- weight transpose: W[k][n] f32 -> WT[n][k] bf16 (Wk,Wv,Wo) ----------------
__global__ __launch_bounds__(256) void wtrans_kernel(
    const float* __restrict__ W0, const float* __restrict__ W1,
    const float* __restrict__ W2, u16* __restrict__ WT) {
  __shared__ u16 tl[32][33];
  int z = blockIdx.z;
  const float* W = (z == 0) ? W0 : (z == 1) ? W1 : W2;
  u16* dst = WT + (size_t)z * C_ * C_;
  int n0 = blockIdx.x * 32, k0 = blockIdx.y * 32;
  int tx = threadIdx.x, ty = threadIdx.y;
#pragma unroll
  for (int i = 0; i < 4; ++i) {
    int k = k0 + ty + i * 8;
    tl[ty + i * 8][tx] = f2bf(W[(size_t)k * C_ + n0 + tx]);
  }
  __syncthreads();
#pragma unroll
  for (int i = 0; i < 4; ++i) {
    int nn = ty + i * 8;
    dst[(size_t)(n0 + nn) * C_ + k0 + tx] = tl[tx][nn];
  }
}

// ---------------- keys f32 (strided in memory_kv) -> int8 [b][m][c], scale 24 ----------------
__global__ __launch_bounds__(256) void prep_keys_kernel(
    const float* __restrict__ mem, char* __restrict__ ki) {
  const int n4 = B_ * M_ * C_ / 4;
  for (int i = blockIdx.x * 256 + threadIdx.x; i < n4; i += gridDim.x * 256) {
    int row = i >> 7;
    int c4 = i & 127;
    f32x4 v = *(const f32x4*)(mem + ((size_t)row * 1024) + c4 * 4);
    u8x4 o;
    o[0] = q8(v[0], KSCALE_); o[1] = q8(v[1], KSCALE_);
    o[2] = q8(v[2], KSCALE_); o[3] = q8(v[3], KSCALE_);
    *(u8x4*)((unsigned char*)ki + (size_t)i * 4) = o;
  }
}

// ---------------- layernorm: x f32 -> xn bf16 + xnf f32 ----------------
__global__ __launch_bounds__(256) void ln_kernel(
    const float* __restrict__ x, const float* __restrict__ w,
    const float* __restrict__ bia, u16* __restrict__ xn, float* __restrict__ xnf) {
  int row = blockIdx.x * 4 + (threadIdx.x >> 6);
  int lane = threadIdx.x & 63;
  const float* xr = x + (size_t)row * C_;
  f32x4 v0 = *(const f32x4*)(xr + lane * 4);
  f32x4 v1 = *(const f32x4*)(xr + 256 + lane * 4);
  float s = v0[0] + v0[1] + v0[2] + v0[3] + v1[0] + v1[1] + v1[2] + v1[3];
  float q = v0[0]*v0[0]+v0[1]*v0[1]+v0[2]*v0[2]+v0[3]*v0[3]
          + v1[0]*v1[0]+v1[1]*v1[1]+v1[2]*v1[2]+v1[3]*v1[3];
#pragma unroll
  for (int m = 1; m < 64; m <<= 1) { s += __shfl_xor(s, m); q += __shfl_xor(q, m); }
  float mean = s * (1.0f / C_);
  float var  = q * (1.0f / C_) - mean * mean;
  float rs = rsqrtf(var + 1e-5f);
  u16x4 o0, o1;
  f32x4 f0, f1;
#pragma unroll
  for (int e = 0; e < 4; ++e) {
    int c = lane * 4 + e;
    f0[e] = (v0[e] - mean) * rs * w[c] + bia[c];
    o0[e] = f2bf(f0[e]);
    int c2 = 256 + lane * 4 + e;
    f1[e] = (v1[e] - mean) * rs * w[c2] + bia[c2];
    o1[e] = f2bf(f1[e]);
  }
  *(u16x4*)(xn + (size_t)row * C_ + lane * 4) = o0;
  *(u16x4*)(xn + (size_t)row * C_ + 256 + lane * 4) = o1;
  *(f32x4*)(xnf + (size_t)row * C_ + lane * 4) = f0;
  *(f32x4*)(xnf + (size_t)row * C_ + 256 + lane * 4) = f1;
}

// ---------------- exact f32 GEMM (for q): C = A(2048x512) * Bw(512x512) + bias ----------------
__global__ __launch_bounds__(256) void gemm_f32(
    const float* __restrict__ A, const float* __restrict__ Bw,
    const float* __restrict__ bias, float* __restrict__ Cout) {
  __shared__ float As[64][33];
  __shared__ float Bs[32][64];
  int tid = threadIdx.x;
  int tx = tid & 15, ty = tid >> 4;
  int r0 = blockIdx.x * 64, c0 = blockIdx.y * 64;
  f32x4 acc[4];
#pragma unroll
  for (int i = 0; i < 4; ++i) acc[i] = f32x4{0.f, 0.f, 0.f, 0.f};
  for (int kt = 0; kt < 16; ++kt) {
    int k0 = kt * 32;
#pragma unroll
    for (int i2 = 0; i2 < 2; ++i2) {
      int idx = i2 * 256 + tid;
      int arow = idx >> 3, ac = idx & 7;
      f32x4 av = *(const f32x4*)(A + (size_t)(r0 + arow) * 512 + k0 + ac * 4);
      As[arow][ac * 4 + 0] = av[0]; As[arow][ac * 4 + 1] = av[1];
      As[arow][ac * 4 + 2] = av[2]; As[arow][ac * 4 + 3] = av[3];
      int krow = idx >> 4, cc = idx & 15;
      f32x4 bv = *(const f32x4*)(Bw + (size_t)(k0 + krow) * 512 + c0 + cc * 4);
      *(f32x4*)(&Bs[krow][cc * 4]) = bv;
    }
    __syncthreads();
#pragma unroll
    for (int kk = 0; kk < 32; ++kk) {
      f32x4 bv = *(const f32x4*)(&Bs[kk][tx * 4]);
#pragma unroll
      for (int i = 0; i < 4; ++i) {
        float av = As[ty * 4 + i][kk];
        acc[i] += av * bv;
      }
    }
    __syncthreads();
  }
  f32x4 bb = *(const f32x4*)(bias + c0 + tx * 4);
#pragma unroll
  for (int i = 0; i < 4; ++i)
    *(f32x4*)(Cout + (size_t)(r0 + ty * 4 + i) * 512 + c0 + tx * 4) = acc[i] + bb;
}

// ---------------- generic 128x128 bf16 MFMA GEMM (f32 out + bias; z selects bias/bias2) -------
__global__ __launch_bounds__(256) void gemm128(
    const u16* __restrict__ A, long aBS,
    const u16* __restrict__ Bt, long bBS,
    float* __restrict__ Cf, long cBS,
    const float* __restrict__ bias, const float* __restrict__ bias2, int ldc) {
  __shared__ __align__(16) u16 As[128 * 64];
  __shared__ __align__(16) u16 Bs[128 * 64];
  const int tid = threadIdx.x;
  const int lane = tid & 63, w = tid >> 6;
  const int wm = w >> 1, wn = w & 1;
  const int z = blockIdx.z;
  const u16* Ab = A + (size_t)z * aBS + (size_t)blockIdx.x * 128 * 512;
  const u16* Bb = Bt + (size_t)z * bBS + (size_t)blockIdx.y * 128 * 512;

  f32x4 acc[4][4];
#pragma unroll
  for (int i = 0; i < 4; ++i)
#pragma unroll
    for (int j = 0; j < 4; ++j) acc[i][j] = f32x4{0.f, 0.f, 0.f, 0.f};

  for (int kt = 0; kt < 8; ++kt) {
    const u16* Akt = Ab + kt * 64;
    const u16* Bkt = Bb + kt * 64;
#pragma unroll
    for (int it = 0; it < 4; ++it) {
      int slot = it * 256 + tid;
      int rr = slot >> 3, ss = slot & 7;
      int q = ss ^ (rr & 7);
      gl_lds16(Akt + (size_t)rr * 512 + q * 8, (char*)As + slot * 16);
      gl_lds16(Bkt + (size_t)rr * 512 + q * 8, (char*)Bs + slot * 16);
    }
    __syncthreads();
#pragma unroll
    for (int kk = 0; kk < 2; ++kk) {
      bf16x8 av[4], bv[4];
#pragma unroll
      for (int i = 0; i < 4; ++i) {
        int blk = kk * 4 + (lane >> 4);
        int ra = wm * 64 + i * 16 + (lane & 15);
        av[i] = *(const bf16x8*)((const char*)As + ra * 128 + ((blk ^ (ra & 7)) << 4));
        int rb = wn * 64 + i * 16 + (lane & 15);
        bv[i] = *(const bf16x8*)((const char*)Bs + rb * 128 + ((blk ^ (rb & 7)) << 4));
      }
#pragma unroll
      for (int mi = 0; mi < 4; ++mi)
#pragma unroll
        for (int ni = 0; ni < 4; ++ni)
          acc[mi][ni] = __builtin_amdgcn_mfma_f32_16x16x32_bf16(av[mi], bv[ni], acc[mi][ni], 0, 0, 0);
    }
    __syncthreads();
  }
  const float* bi = (z == 1 && bias2) ? bias2 : bias;
  const long cbase = (long)z * cBS;
  const int rsub = (lane >> 4) * 4;
  const long row0 = (long)blockIdx.x * 128 + wm * 64;
  const int col00 = wn * 64 + (lane & 15) + (int)blockIdx.y * 128;
#pragma unroll
  for (int mi = 0; mi < 4; ++mi)
#pragma unroll
    for (int rg = 0; rg < 4; ++rg) {
      long row = row0 + mi * 16 + rsub + rg;
#pragma unroll
      for (int ni = 0; ni < 4; ++ni) {
        int col = col00 + ni * 16;
        float bb = bi ? bi[col] : 0.0f;
        Cf[cbase + row * (long)ldc + col] = acc[mi][ni][rg] + bb;
      }
    }
}

// ---------------- scores GEMM int8, double-buffered 2-phase, XCD-swizzled ----------------
// p%8 == coltile%8 so all 8 rowtiles sharing a key-tile land on one XCD (L2-resident B).
__global__ __launch_bounds__(256) void gemm_sc8(
    const char* __restrict__ A, const char* __restrict__ Bt, char* __restrict__ sc8) {
  __shared__ __align__(16) char As[2][128 * 64];
  __shared__ __align__(16) char Bs[2][128 * 64];
  const int tid = threadIdx.x;
  const int lane = tid & 63, w = tid >> 6;
  const int wm = w >> 1, wn = w & 1;
  const int p = blockIdx.x;
  const int z = p >> 11;
  const int q_ = p & 2047;
  const int r = (q_ >> 3) & 7;                     // row tile [0,8)
  const int c = ((q_ >> 6) << 3) | (q_ & 7);       // col tile [0,256)
  const char* Ab = A + (size_t)z * T_ * C_ + (size_t)r * 128 * 512;
  const char* Bb = Bt + (size_t)z * M_ * C_ + (size_t)c * 128 * 512;

  i32x4 acc[4][4];
#pragma unroll
  for (int i = 0; i < 4; ++i)
#pragma unroll
    for (int j = 0; j < 4; ++j) acc[i][j] = i32x4{0, 0, 0, 0};

  auto STAGE = [&](int buf, int kt) {
    const char* Akt = Ab + kt * 64;
    const char* Bkt = Bb + kt * 64;
#pragma unroll
    for (int it = 0; it < 2; ++it) {
      int slot = it * 256 + tid;
      int rr = slot >> 2, cw = slot & 3;
      int ch = cw ^ (rr & 3);
      gl_lds16(Akt + (size_t)rr * 512 + ch * 16, As[buf] + slot * 16);
      gl_lds16(Bkt + (size_t)rr * 512 + ch * 16, Bs[buf] + slot * 16);
    }
  };

  STAGE(0, 0);
  __syncthreads();
  int cur = 0;
  for (int kt = 0; kt < 8; ++kt) {
    if (kt < 7) STAGE(cur ^ 1, kt + 1);   // in flight during this tile's compute
    i32x4 av[4], bv[4];
#pragma unroll
    for (int i = 0; i < 4; ++i) {
      int ra = wm * 64 + i * 16 + (lane & 15);
      av[i] = *(const i32x4*)(As[cur] + ra * 64 + (((lane >> 4) ^ (ra & 3)) << 4));
      int rb = wn * 64 + i * 16 + (lane & 15);
      bv[i] = *(const i32x4*)(Bs[cur] + rb * 64 + (((lane >> 4) ^ (rb & 3)) << 4));
    }
#pragma unroll
    for (int mi = 0; mi < 4; ++mi)
#pragma unroll
      for (int ni = 0; ni < 4; ++ni)
        acc[mi][ni] = __builtin_amdgcn_mfma_i32_16x16x64_i8(av[mi], bv[ni], acc[mi][ni], 0, 0, 0);
    __syncthreads();   // drains next-tile staging (overlapped with the MFMAs above)
    cur ^= 1;
  }
  const int rsub = (lane >> 4) * 4;
  const long row0 = (long)r * 128 + wm * 64;
  const int col00 = c * 128 + wn * 64 + (lane & 15);
  char* base = sc8 + (size_t)z * T_ * M_;
  const float osc = OSCALE_ / (QSCALE_ * KSCALE_);
#pragma unroll
  for (int mi = 0; mi < 4; ++mi)
#pragma unroll
    for (int rg = 0; rg < 4; ++rg) {
      long row = row0 + mi * 16 + rsub + rg;
#pragma unroll
      for (int ni = 0; ni < 4; ++ni) {
        int iv = (int)rintf((float)acc[mi][ni][rg] * osc);
        iv = iv > 127 ? 127 : (iv < -127 ? -127 : iv);
        base[row * (long)M_ + col00 + ni * 16] = (char)iv;
      }
    }
}

// ---------------- postprocess: l2norm q,k; emit outputs + q int8 ----------------
__global__ __launch_bounds__(256) void postproc_kernel(
    const float* __restrict__ qraw, const float* __restrict__ kraw,
    const float* __restrict__ vraw, float* __restrict__ qf,
    u16* __restrict__ qb, u16* __restrict__ kb, char* __restrict__ qi,
    float* __restrict__ kvout) {
  int row = blockIdx.x * 4 + (threadIdx.x >> 6);
  int lane = threadIdx.x & 63;
  size_t rb_ = (size_t)row * C_;
  f32x4 a0 = *(const f32x4*)(qraw + rb_ + lane * 4);
  f32x4 a1 = *(const f32x4*)(qraw + rb_ + 256 + lane * 4);
  float ss = a0[0]*a0[0]+a0[1]*a0[1]+a0[2]*a0[2]+a0[3]*a0[3]
           + a1[0]*a1[0]+a1[1]*a1[1]+a1[2]*a1[2]+a1[3]*a1[3];
#pragma unroll
  for (int m = 1; m < 64; m <<= 1) ss += __shfl_xor(ss, m);
  float rn = 1.0f / fmaxf(sqrtf(ss), 1e-12f);
  f32x4 q0 = a0 * rn, q1 = a1 * rn;
  *(f32x4*)(qf + rb_ + lane * 4) = q0;
  *(f32x4*)(qf + rb_ + 256 + lane * 4) = q1;
  u16x4 t0, t1;
#pragma unroll
  for (int e = 0; e < 4; ++e) { t0[e] = f2bf(q0[e]); t1[e] = f2bf(q1[e]); }
  *(u16x4*)(qb + rb_ + lane * 4) = t0;
  *(u16x4*)(qb + rb_ + 256 + lane * 4) = t1;
  u8x4 i0, i1;
#pragma unroll
  for (int e = 0; e < 4; ++e) { i0[e] = q8(q0[e], QSCALE_); i1[e] = q8(q1[e], QSCALE_); }
  *(u8x4*)((unsigned char*)qi + rb_ + lane * 4) = i0;
  *(u8x4*)((unsigned char*)qi + rb_ + 256 + lane * 4) = i1;
  f32x4 b0 = *(const f32x4*)(kraw + rb_ + lane * 4);
  f32x4 b1 = *(const f32x4*)(kraw + rb_ + 256 + lane * 4);
  float sk = b0[0]*b0[0]+b0[1]*b0[1]+b0[2]*b0[2]+b0[3]*b0[3]
           + b1[0]*b1[0]+b1[1]*b1[1]+b1[2]*b1[2]+b1[3]*b1[3];
#pragma unroll
  for (int m = 1; m < 64; m <<= 1) sk += __shfl_xor(sk, m);
  float rk = 1.0f / fmaxf(sqrtf(sk), 1e-12f);
  f32x4 k0 = b0 * rk, k1 = b1 * rk;
  size_t kvb = (size_t)row * (2 * C_);
  *(f32x4*)(kvout + kvb + lane * 4) = k0;
  *(f32x4*)(kvout + kvb + 256 + lane * 4) = k1;
#pragma unroll
  for (int e = 0; e < 4; ++e) { t0[e] = f2bf(k0[e]); t1[e] = f2bf(k1[e]); }
  *(u16x4*)(kb + rb_ + lane * 4) = t0;
  *(u16x4*)(kb + rb_ + 256 + lane * 4) = t1;
  f32x4 c0 = *(const f32x4*)(vraw + rb_ + lane * 4);
  f32x4 c1 = *(const f32x4*)(vraw + rb_ + 256 + lane * 4);
  *(f32x4*)(kvout + kvb + C_ + lane * 4) = c0;
  *(f32x4*)(kvout + kvb + C_ + 256 + lane * 4) = c1;
}

// ---------------- V transpose -> vT bf16 [b][h][d][t] ----------------
__global__ __launch_bounds__(256) void vtrans_kernel(
    const float* __restrict__ vraw, u16* __restrict__ vT) {
  __shared__ u16 tile[64][65];
  int tt = blockIdx.x, h = blockIdx.y, b = blockIdx.z;
  int tx = threadIdx.x, ty = threadIdx.y;
#pragma unroll
  for (int i = 0; i < 8; ++i) {
    int t = tt * 64 + ty + i * 8;
    const float* src = vraw + (size_t)(b * T_ + t) * C_ + h * 64;
    tile[ty + i * 8][tx] = f2bf(src[tx]);
    tile[ty + i * 8][tx + 32] = f2bf(src[tx + 32]);
  }
  __syncthreads();
#pragma unroll
  for (int i = 0; i < 8; ++i) {
    int d = ty + i * 8;
    u16* dst = vT + ((size_t)((b * H_ + h) * 64 + d)) * T_ + tt * 64;
    dst[tx] = tile[tx][d];
    dst[tx + 32] = tile[tx + 32][d];
  }
}

// ---------------- causal flash attention, 64 q-rows/block (256 blocks) ----------------
__global__ __launch_bounds__(256) void attn_kernel(
    const u16* __restrict__ qb, const u16* __restrict__ kb,
    const u16* __restrict__ vT, float* __restrict__ o) {
  __shared__ __align__(16) u16 Ks[128 * 64];
  __shared__ __align__(16) u16 Vs[64 * 128];
  __shared__ __align__(16) u16 Ps[4][16 * 128];
  int tid = threadIdx.x, lane = tid & 63, w = tid >> 6;
  int it = blockIdx.x, h = blockIdx.y, b = blockIdx.z;
  int t0 = it * 64;
  bf16x8 aq[2];
#pragma unroll
  for (int kk = 0; kk < 2; ++kk) {
    int row = t0 + w * 16 + (lane & 15);
    aq[kk] = *(const bf16x8*)(qb + (size_t)(b * T_ + row) * C_ + h * 64 + kk * 32 + (lane >> 4) * 8);
  }
  f32x4 accO[4];
  float denp[4];
#pragma unroll
  for (int j = 0; j < 4; ++j) { accO[j] = f32x4{0.f,0.f,0.f,0.f}; denp[j] = 0.f; }

  int ntiles = it / 2 + 1;
  for (int jt = 0; jt < ntiles; ++jt) {
    int j0 = jt * 128;
#pragma unroll
    for (int i2 = 0; i2 < 4; ++i2) {
      int slot = i2 * 256 + tid;
      int rr = slot >> 3, ssw = slot & 7;
      int q = ssw ^ (rr & 7);
      gl_lds16(kb + (size_t)(b * T_ + j0 + rr) * C_ + h * 64 + q * 8, (char*)Ks + slot * 16);
    }
#pragma unroll
    for (int i2 = 0; i2 < 4; ++i2) {
      int slot = i2 * 256 + tid;
      int rr = slot >> 4, ssw = slot & 15;
      int q = ssw ^ (rr & 15);
      gl_lds16(vT + ((size_t)((b * H_ + h) * 64 + rr)) * T_ + j0 + q * 8, (char*)Vs + slot * 16);
    }
    __syncthreads();
    f32x4 s[8];
#pragma unroll
    for (int ni = 0; ni < 8; ++ni) s[ni] = f32x4{0.f,0.f,0.f,0.f};
#pragma unroll
    for (int kk = 0; kk < 2; ++kk) {
      bf16x8 bk[8];
#pragma unroll
      for (int ni = 0; ni < 8; ++ni) {
        int rbi = ni * 16 + (lane & 15);
        int blk = kk * 4 + (lane >> 4);
        bk[ni] = *(const bf16x8*)((const char*)Ks + rbi * 128 + ((blk ^ (rbi & 7)) << 4));
      }
#pragma unroll
      for (int ni = 0; ni < 8; ++ni)
        s[ni] = __builtin_amdgcn_mfma_f32_16x16x32_bf16(aq[kk], bk[ni], s[ni], 0, 0, 0);
    }
#pragma unroll
    for (int ni = 0; ni < 8; ++ni)
#pragma unroll
      for (int rg = 0; rg < 4; ++rg) {
        int qrow = t0 + w * 16 + (lane >> 4) * 4 + rg;
        int kvcol = j0 + ni * 16 + (lane & 15);
        float sv = s[ni][rg] * SCALE_;
        float p = (kvcol <= qrow) ? __expf(sv) : 0.0f;
        denp[rg] += p;
        int qk = (lane >> 4) * 4 + rg;
        int kvl = ni * 16 + (lane & 15);
        int blk2 = kvl >> 3;
        *(u16*)((char*)Ps[w] + qk * 256 + ((blk2 ^ qk) << 4) + (kvl & 7) * 2) = f2bf(p);
      }
#pragma unroll
    for (int kk2 = 0; kk2 < 4; ++kk2) {
      bf16x8 ap, bvv[4];
      int blk = kk2 * 4 + (lane >> 4);
      int rq = lane & 15;
      ap = *(const bf16x8*)((const char*)Ps[w] + rq * 256 + ((blk ^ rq) << 4));
#pragma unroll
      for (int nd = 0; nd < 4; ++nd) {
        int rd = nd * 16 + (lane & 15);
        bvv[nd] = *(const bf16x8*)((const char*)Vs + rd * 256 + ((blk ^ (rd & 15)) << 4));
      }
#pragma unroll
      for (int nd = 0; nd < 4; ++nd)
        accO[nd] = __builtin_amdgcn_mfma_f32_16x16x32_bf16(ap, bvv[nd], accO[nd], 0, 0, 0);
    }
    __syncthreads();
  }
  float den[4];
#pragma unroll
  for (int rg = 0; rg < 4; ++rg) {
    float d = denp[rg];
    d += __shfl_xor(d, 1); d += __shfl_xor(d, 2);
    d += __shfl_xor(d, 4); d += __shfl_xor(d, 8);
    den[rg] = d;
  }
#pragma unroll
  for (int nd = 0; nd < 4; ++nd)
#pragma unroll
    for (int rg = 0; rg < 4; ++rg) {
      int row = t0 + w * 16 + (lane >> 4) * 4 + rg;
      int d = nd * 16 + (lane & 15);
      o[(size_t)(b * T_ + row) * C_ + h * 64 + d] = accO[nd][rg] / den[rg];
    }
}

// ---------------- approx top-64 candidates per row from int8 scores ----------------
__global__ __launch_bounds__(256) void topk_kernel(
    const char* __restrict__ scores, int* __restrict__ cand) {
  int row = blockIdx.x;
  const unsigned char* s = (const unsigned char*)scores + (size_t)row * M_;
  int tid = threadIdx.x, lane = tid & 63, w = tid >> 6;
  unsigned c[8];
#pragma unroll
  for (int i = 0; i < 8; ++i) c[i] = 0;
  for (int i2 = 0; i2 < 16; ++i2) {
    int base = i2 * 2048 + tid * 8;
    uint2 v = *(const uint2*)(s + base);
#pragma unroll
    for (int e = 0; e < 8; ++e) {
      unsigned byte = (e < 4) ? ((v.x >> (8 * e)) & 0xFF) : ((v.y >> (8 * (e - 4))) & 0xFF);
      unsigned key = byte ^ 0x80u;
      unsigned cmb = (key << 15) | (unsigned)(32767 - (base + e));
      if (cmb > c[7]) {
        c[7] = cmb;
#pragma unroll
        for (int ss = 7; ss > 0; --ss) {
          if (c[ss] > c[ss - 1]) { unsigned t = c[ss - 1]; c[ss - 1] = c[ss]; c[ss] = t; }
        }
      }
    }
  }
  __shared__ unsigned red[4];
  __shared__ unsigned winner;
  for (int r = 0; r < NCAND_; ++r) {
    unsigned bb = c[0];
#pragma unroll
    for (int m = 1; m < 64; m <<= 1) {
      unsigned o = __shfl_xor(bb, m);
      bb = (o > bb) ? o : bb;
    }
    if (lane == 0) red[w] = bb;
    __syncthreads();
    if (tid == 0) {
      unsigned m0 = red[0];
      if (red[1] > m0) m0 = red[1];
      if (red[2] > m0) m0 = red[2];
      if (red[3] > m0) m0 = red[3];
      winner = m0;
      cand[(size_t)row * NCAND_ + r] = 32767 - (int)(m0 & 32767u);
    }
    __syncthreads();
    unsigned win = winner;
    if (c[0] == win) {
#pragma unroll
      for (int ss = 0; ss < 7; ++ss) c[ss] = c[ss + 1];
      c[7] = 0;
    }
    __syncthreads();
  }
}

// ---------------- fused tail: exact f32 rescore -> top-32 -> mem attention -> combine ----------------
__global__ __launch_bounds__(256) void knn_tail_kernel(
    const float* __restrict__ qf, const float* __restrict__ mem,
    const int* __restrict__ cand, const float* __restrict__ attn,
    const float* __restrict__ gate, u16* __restrict__ comb) {
  int row = blockIdx.x, b = row >> 10;
  int tid = threadIdx.x, lane = tid & 63, w = tid >> 6;
  __shared__ float qL[512];
  __shared__ float sL[NCAND_];
  __shared__ float sHh[NCAND_][8];
  __shared__ int cL[NCAND_];
  __shared__ int wIdx[TOPK_];
  __shared__ float eL[TOPK_][8];
  qL[tid] = qf[(size_t)row * C_ + tid];
  qL[256 + tid] = qf[(size_t)row * C_ + 256 + tid];
  if (tid < NCAND_) cL[tid] = cand[(size_t)row * NCAND_ + tid];
  __syncthreads();
  // phase 1: exact rescore of 64 candidates (key halves), 16 per wave
#pragma unroll 4
  for (int i = 0; i < 16; ++i) {
    int cdx = w * 16 + i;
    const float* mrow = mem + ((size_t)(b * M_ + cL[cdx])) * 1024;
    f32x4 k0 = *(const f32x4*)(mrow + lane * 8);
    f32x4 k1 = *(const f32x4*)(mrow + lane * 8 + 4);
    float p = qL[lane*8+0]*k0[0] + qL[lane*8+1]*k0[1] + qL[lane*8+2]*k0[2] + qL[lane*8+3]*k0[3]
            + qL[lane*8+4]*k1[0] + qL[lane*8+5]*k1[1] + qL[lane*8+6]*k1[2] + qL[lane*8+7]*k1[3];
    p += __shfl_xor(p, 1); p += __shfl_xor(p, 2); p += __shfl_xor(p, 4);
    if ((lane & 7) == 0) sHh[cdx][lane >> 3] = p;
    float pf = p;
    pf += __shfl_xor(pf, 8); pf += __shfl_xor(pf, 16); pf += __shfl_xor(pf, 32);
    if (lane == 0) sL[cdx] = pf;
  }
  __syncthreads();
  // phase 2: exact ranking (score desc, index asc)
  if (tid < NCAND_) {
    float sv = sL[tid]; int id = cL[tid];
    int rank = 0;
#pragma unroll
    for (int j = 0; j < NCAND_; ++j) {
      float sj = sL[j];
      rank += (sj > sv) || (sj == sv && cL[j] < id);
    }
    if (rank < TOPK_) {
      wIdx[rank] = id;
#pragma unroll
      for (int h = 0; h < 8; ++h)
        eL[rank][h] = __expf(sHh[tid][h] * SCALE_);
    }
  }
  __syncthreads();
  // phase 3: gather v of winners, weighted sum, combine with causal attn
  int h2 = tid >> 5, dp = tid & 31;
  float num0 = 0.f, num1 = 0.f, den = 0.f;
#pragma unroll 8
  for (int k = 0; k < TOPK_; ++k) {
    float wgt = eL[k][h2];
    const float* vrow = mem + ((size_t)(b * M_ + wIdx[k])) * 1024 + 512;
    f32x2 vv = *(const f32x2*)(vrow + h2 * 64 + dp * 2);
    num0 += wgt * vv[0];
    num1 += wgt * vv[1];
    den += wgt;
  }
  float g = gate[h2];
  int c0 = h2 * 64 + dp * 2;
  float a0 = attn[(size_t)row * C_ + c0];
  float a1 = attn[(size_t)row * C_ + c0 + 1];
  u16 o0 = f2bf(g * (num0 / den) + (1.0f - g) * a0);
  u16 o1 = f2bf(g * (num1 / den) + (1.0f - g) * a1);
  *(unsigned*)(comb + (size_t)row * C_ + c0) = (unsigned)o0 | ((unsigned)o1 << 16);
}

extern "C" void kernel_launch(void* const* d_in, const int* in_sizes, int n_in,
                              void* d_out, int out_size, void* d_ws, size_t ws_size,
                              hipStream_t stream) {
  const float* x    = (const float*)d_in[0];
  const float* mem  = (const float*)d_in[1];
  const float* lnw  = (const float*)d_in[2];
  const float* lnb  = (const float*)d_in[3];
  const float* Wq   = (const float*)d_in[4];
  const float* bq   = (const float*)d_in[5];
  const float* Wk   = (const float*)d_in[6];
  const float* bk   = (const float*)d_in[7];
  const float* Wv   = (const float*)d_in[8];
  const float* bv   = (const float*)d_in[9];
  const float* Wo   = (const float*)d_in[10];
  const float* bo   = (const float*)d_in[11];
  const float* gate = (const float*)d_in[12];
  float* out   = (float*)d_out;
  float* kvout = out + (size_t)B_ * T_ * C_;

  size_t off = 0;
  auto alloc = [&](size_t bytes) {
    char* r = (char*)d_ws + off;
    off += (bytes + 255) & ~(size_t)255;
    return r;
  };
  u16*      WT   = (u16*)alloc(3ull * C_ * C_ * 2);
  char*     ki   = (char*)alloc((size_t)B_ * M_ * C_);
  u16*      xn   = (u16*)alloc((size_t)B_ * T_ * C_ * 2);
  float*    xnf  = (float*)alloc((size_t)B_ * T_ * C_ * 4);
  float*    qraw = (float*)alloc((size_t)B_ * T_ * C_ * 4);
  float*    kvraw= (float*)alloc(2ull * B_ * T_ * C_ * 4);
  float*    kraw = kvraw;
  float*    vraw = kvraw + (size_t)B_ * T_ * C_;
  float*    qf   = (float*)alloc((size_t)B_ * T_ * C_ * 4);
  u16*      qb   = (u16*)alloc((size_t)B_ * T_ * C_ * 2);
  u16*      kb   = (u16*)alloc((size_t)B_ * T_ * C_ * 2);
  char*     qi   = (char*)alloc((size_t)B_ * T_ * C_);
  u16*      vT   = (u16*)alloc((size_t)B_ * T_ * C_ * 2);
  float*    attn = (float*)alloc((size_t)B_ * T_ * C_ * 4);
  char*     sc8  = (char*)alloc((size_t)B_ * T_ * M_);
  int*      candb= (int*)alloc((size_t)B_ * T_ * NCAND_ * 4);
  u16*      comb = (u16*)alloc((size_t)B_ * T_ * C_ * 2);
  if (off > ws_size) return;

  wtrans_kernel<<<dim3(16, 16, 3), dim3(32, 8), 0, stream>>>(Wk, Wv, Wo, WT);
  prep_keys_kernel<<<8192, 256, 0, stream>>>(mem, ki);
  ln_kernel<<<512, 256, 0, stream>>>(x, lnw, lnb, xn, xnf);
  gemm_f32<<<dim3(32, 8), 256, 0, stream>>>(xnf, Wq, bq, qraw);
  gemm128<<<dim3(16, 4, 2), 256, 0, stream>>>(xn, 0, WT, (long)C_ * C_,
                                              kvraw, (long)B_ * T_ * C_, bk, bv, C_);
  postproc_kernel<<<512, 256, 0, stream>>>(qraw, kraw, vraw, qf, qb, kb, qi, kvout);
  vtrans_kernel<<<dim3(16, 8, 2), dim3(32, 8), 0, stream>>>(vraw, vT);
  attn_kernel<<<dim3(16, 8, 2), 256, 0, stream>>>(qb, kb, vT, attn);
  gemm_sc8<<<4096, 256, 0, stream>>>(qi, ki, sc8);
  topk_kernel<<<2048, 256, 0, stream>>>(sc8, candb);
  knn_tail_kernel<<<2048, 256, 0, stream>>>(qf, mem, candb, attn, gate, comb);
  gemm128<<<dim3(16, 4, 1), 256, 0, stream>>>(comb, 0, WT + 2 * C_ * C_, 0,
                                              out, 0, bo, nullptr, C_);
}

// Round 8
// 326.324 us; speedup vs baseline: 1.0898x; 1.0898x over previous
//
#include <hip/hip_runtime.h>
#include <hip/hip_bf16.h>

#define B_ 2
#define T_ 1024
#define H_ 8
#define D_ 64
#define C_ 512
#define M_ 32768
#define TOPK_ 32
#define NCAND_ 64
#define SCALE_ 0.125f
#define QSCALE_ 360.0f
#define KSCALE_ 24.0f
#define OSCALE_ 20.0f

typedef unsigned short u16;
typedef float    f32x2  __attribute__((ext_vector_type(2)));
typedef float    f32x4  __attribute__((ext_vector_type(4)));
typedef __bf16   bf16x8 __attribute__((ext_vector_type(8)));
typedef u16      u16x4  __attribute__((ext_vector_type(4)));
typedef int      i32x4  __attribute__((ext_vector_type(4)));
typedef unsigned char u8x4 __attribute__((ext_vector_type(4)));

__device__ __forceinline__ u16 f2bf(float f) {
  __hip_bfloat16 b = __float2bfloat16(f);
  u16 u; __builtin_memcpy(&u, &b, 2); return u;
}

__device__ __forceinline__ unsigned char q8(float v, float scale) {
  int iv = (int)rintf(v * scale);
  iv = iv > 127 ? 127 : (iv < -127 ? -127 : iv);
  return (unsigned char)(signed char)iv;
}

__device__ __forceinline__ void gl_lds16(const void* g, void* l) {
  __builtin_amdgcn_global_load_lds(
      (const __attribute__((address_space(1))) void*)g,
      (__attribute__((address_space(3))) void*)l, 16, 0, 0);
}

// ---------------- weight transpose: W[k][n] f32 -> WT[n][k] bf16 (Wk,Wv,Wo) ----------------
__global__ __launch_bounds__(256) void wtrans_kernel(
    const float* __restrict__ W0, const float* __restrict__ W1,
    const float* __restrict__ W2, u16* __restrict__ WT) {
  __shared__ u16 tl[32][33];
  int z = blockIdx.z;
  const float* W = (z == 0) ? W0 : (z == 1) ? W1 : W2;
  u16* dst = WT + (size_t)z * C_ * C_;
  int n0 = blockIdx.x * 32, k0 = blockIdx.y * 32;
  int tx = threadIdx.x, ty = threadIdx.y;
#pragma unroll
  for (int i = 0; i < 4; ++i) {
    int k = k0 + ty + i * 8;
    tl[ty + i * 8][tx] = f2bf(W[(size_t)k * C_ + n0 + tx]);
  }
  __syncthreads();
#pragma unroll
  for (int i = 0; i < 4; ++i) {
    int nn = ty + i * 8;
    dst[(size_t)(n0 + nn) * C_ + k0 + tx] = tl[tx][nn];
  }
}

// ---------------- keys f32 (strided in memory_kv) -> int8 [b][m][c], scale 24 ----------------
__global__ __launch_bounds__(256) void prep_keys_kernel(
    const float* __restrict__ mem, char* __restrict__ ki) {
  const int n4 = B_ * M_ * C_ / 4;
  for (int i = blockIdx.x * 256 + threadIdx.x; i < n4; i += gridDim.x * 256) {
    int row = i >> 7;
    int c4 = i & 127;
    f32x4 v = *(const f32x4*)(mem + ((size_t)row * 1024) + c4 * 4);
    u8x4 o;
    o[0] = q8(v[0], KSCALE_); o[1] = q8(v[1], KSCALE_);
    o[2] = q8(v[2], KSCALE_); o[3] = q8(v[3], KSCALE_);
    *(u8x4*)((unsigned char*)ki + (size_t)i * 4) = o;
  }
}

// ---------------- layernorm: x f32 -> xn bf16 + xnf f32 ----------------
__global__ __launch_bounds__(256) void ln_kernel(
    const float* __restrict__ x, const float* __restrict__ w,
    const float* __restrict__ bia, u16* __restrict__ xn, float* __restrict__ xnf) {
  int row = blockIdx.x * 4 + (threadIdx.x >> 6);
  int lane = threadIdx.x & 63;
  const float* xr = x + (size_t)row * C_;
  f32x4 v0 = *(const f32x4*)(xr + lane * 4);
  f32x4 v1 = *(const f32x4*)(xr + 256 + lane * 4);
  float s = v0[0] + v0[1] + v0[2] + v0[3] + v1[0] + v1[1] + v1[2] + v1[3];
  float q = v0[0]*v0[0]+v0[1]*v0[1]+v0[2]*v0[2]+v0[3]*v0[3]
          + v1[0]*v1[0]+v1[1]*v1[1]+v1[2]*v1[2]+v1[3]*v1[3];
#pragma unroll
  for (int m = 1; m < 64; m <<= 1) { s += __shfl_xor(s, m); q += __shfl_xor(q, m); }
  float mean = s * (1.0f / C_);
  float var  = q * (1.0f / C_) - mean * mean;
  float rs = rsqrtf(var + 1e-5f);
  u16x4 o0, o1;
  f32x4 f0, f1;
#pragma unroll
  for (int e = 0; e < 4; ++e) {
    int c = lane * 4 + e;
    f0[e] = (v0[e] - mean) * rs * w[c] + bia[c];
    o0[e] = f2bf(f0[e]);
    int c2 = 256 + lane * 4 + e;
    f1[e] = (v1[e] - mean) * rs * w[c2] + bia[c2];
    o1[e] = f2bf(f1[e]);
  }
  *(u16x4*)(xn + (size_t)row * C_ + lane * 4) = o0;
  *(u16x4*)(xn + (size_t)row * C_ + 256 + lane * 4) = o1;
  *(f32x4*)(xnf + (size_t)row * C_ + lane * 4) = f0;
  *(f32x4*)(xnf + (size_t)row * C_ + 256 + lane * 4) = f1;
}

// ---------------- exact f32 GEMM (for q): C = A(2048x512) * Bw(512x512) + bias ----------------
__global__ __launch_bounds__(256) void gemm_f32(
    const float* __restrict__ A, const float* __restrict__ Bw,
    const float* __restrict__ bias, float* __restrict__ Cout) {
  __shared__ float As[64][33];
  __shared__ float Bs[32][64];
  int tid = threadIdx.x;
  int tx = tid & 15, ty = tid >> 4;
  int r0 = blockIdx.x * 64, c0 = blockIdx.y * 64;
  f32x4 acc[4];
#pragma unroll
  for (int i = 0; i < 4; ++i) acc[i] = f32x4{0.f, 0.f, 0.f, 0.f};
  for (int kt = 0; kt < 16; ++kt) {
    int k0 = kt * 32;
#pragma unroll
    for (int i2 = 0; i2 < 2; ++i2) {
      int idx = i2 * 256 + tid;
      int arow = idx >> 3, ac = idx & 7;
      f32x4 av = *(const f32x4*)(A + (size_t)(r0 + arow) * 512 + k0 + ac * 4);
      As[arow][ac * 4 + 0] = av[0]; As[arow][ac * 4 + 1] = av[1];
      As[arow][ac * 4 + 2] = av[2]; As[arow][ac * 4 + 3] = av[3];
      int krow = idx >> 4, cc = idx & 15;
      f32x4 bv = *(const f32x4*)(Bw + (size_t)(k0 + krow) * 512 + c0 + cc * 4);
      *(f32x4*)(&Bs[krow][cc * 4]) = bv;
    }
    __syncthreads();
#pragma unroll
    for (int kk = 0; kk < 32; ++kk) {
      f32x4 bv = *(const f32x4*)(&Bs[kk][tx * 4]);
#pragma unroll
      for (int i = 0; i < 4; ++i) {
        float av = As[ty * 4 + i][kk];
        acc[i] += av * bv;
      }
    }
    __syncthreads();
  }
  f32x4 bb = *(const f32x4*)(bias + c0 + tx * 4);
#pragma unroll
  for (int i = 0; i < 4; ++i)
    *(f32x4*)(Cout + (size_t)(r0 + ty * 4 + i) * 512 + c0 + tx * 4) = acc[i] + bb;
}

// ---------------- generic 128x128 bf16 MFMA GEMM (f32 out + bias; z selects bias/bias2) -------
__global__ __launch_bounds__(256) void gemm128(
    const u16* __restrict__ A, long aBS,
    const u16* __restrict__ Bt, long bBS,
    float* __restrict__ Cf, long cBS,
    const float* __restrict__ bias, const float* __restrict__ bias2, int ldc) {
  __shared__ __align__(16) u16 As[128 * 64];
  __shared__ __align__(16) u16 Bs[128 * 64];
  const int tid = threadIdx.x;
  const int lane = tid & 63, w = tid >> 6;
  const int wm = w >> 1, wn = w & 1;
  const int z = blockIdx.z;
  const u16* Ab = A + (size_t)z * aBS + (size_t)blockIdx.x * 128 * 512;
  const u16* Bb = Bt + (size_t)z * bBS + (size_t)blockIdx.y * 128 * 512;

  f32x4 acc[4][4];
#pragma unroll
  for (int i = 0; i < 4; ++i)
#pragma unroll
    for (int j = 0; j < 4; ++j) acc[i][j] = f32x4{0.f, 0.f, 0.f, 0.f};

  for (int kt = 0; kt < 8; ++kt) {
    const u16* Akt = Ab + kt * 64;
    const u16* Bkt = Bb + kt * 64;
#pragma unroll
    for (int it = 0; it < 4; ++it) {
      int slot = it * 256 + tid;
      int rr = slot >> 3, ss = slot & 7;
      int q = ss ^ (rr & 7);
      gl_lds16(Akt + (size_t)rr * 512 + q * 8, (char*)As + slot * 16);
      gl_lds16(Bkt + (size_t)rr * 512 + q * 8, (char*)Bs + slot * 16);
    }
    __syncthreads();
#pragma unroll
    for (int kk = 0; kk < 2; ++kk) {
      bf16x8 av[4], bv[4];
#pragma unroll
      for (int i = 0; i < 4; ++i) {
        int blk = kk * 4 + (lane >> 4);
        int ra = wm * 64 + i * 16 + (lane & 15);
        av[i] = *(const bf16x8*)((const char*)As + ra * 128 + ((blk ^ (ra & 7)) << 4));
        int rb = wn * 64 + i * 16 + (lane & 15);
        bv[i] = *(const bf16x8*)((const char*)Bs + rb * 128 + ((blk ^ (rb & 7)) << 4));
      }
#pragma unroll
      for (int mi = 0; mi < 4; ++mi)
#pragma unroll
        for (int ni = 0; ni < 4; ++ni)
          acc[mi][ni] = __builtin_amdgcn_mfma_f32_16x16x32_bf16(av[mi], bv[ni], acc[mi][ni], 0, 0, 0);
    }
    __syncthreads();
  }
  const float* bi = (z == 1 && bias2) ? bias2 : bias;
  const long cbase = (long)z * cBS;
  const int rsub = (lane >> 4) * 4;
  const long row0 = (long)blockIdx.x * 128 + wm * 64;
  const int col00 = wn * 64 + (lane & 15) + (int)blockIdx.y * 128;
#pragma unroll
  for (int mi = 0; mi < 4; ++mi)
#pragma unroll
    for (int rg = 0; rg < 4; ++rg) {
      long row = row0 + mi * 16 + rsub + rg;
#pragma unroll
      for (int ni = 0; ni < 4; ++ni) {
        int col = col00 + ni * 16;
        float bb = bi ? bi[col] : 0.0f;
        Cf[cbase + row * (long)ldc + col] = acc[mi][ni][rg] + bb;
      }
    }
}

// ---------------- scores GEMM int8 (single-buffered, proven r4), XCD-swizzled ----------------
// p%8 == coltile%8 so all 8 rowtiles sharing a key-tile land on one XCD (L2-resident B).
__global__ __launch_bounds__(256) void gemm_sc8(
    const char* __restrict__ A, const char* __restrict__ Bt, char* __restrict__ sc8) {
  __shared__ __align__(16) char As[128 * 64];
  __shared__ __align__(16) char Bs[128 * 64];
  const int tid = threadIdx.x;
  const int lane = tid & 63, w = tid >> 6;
  const int wm = w >> 1, wn = w & 1;
  const int p = blockIdx.x;
  const int z = p >> 11;
  const int q_ = p & 2047;
  const int r = (q_ >> 3) & 7;                     // row tile [0,8)
  const int c = ((q_ >> 6) << 3) | (q_ & 7);       // col tile [0,256)
  const char* Ab = A + (size_t)z * T_ * C_ + (size_t)r * 128 * 512;
  const char* Bb = Bt + (size_t)z * M_ * C_ + (size_t)c * 128 * 512;

  i32x4 acc[4][4];
#pragma unroll
  for (int i = 0; i < 4; ++i)
#pragma unroll
    for (int j = 0; j < 4; ++j) acc[i][j] = i32x4{0, 0, 0, 0};

  for (int kt = 0; kt < 8; ++kt) {
    const char* Akt = Ab + kt * 64;
    const char* Bkt = Bb + kt * 64;
#pragma unroll
    for (int it = 0; it < 2; ++it) {
      int slot = it * 256 + tid;
      int rr = slot >> 2, cw = slot & 3;
      int ch = cw ^ (rr & 3);
      gl_lds16(Akt + (size_t)rr * 512 + ch * 16, As + slot * 16);
      gl_lds16(Bkt + (size_t)rr * 512 + ch * 16, Bs + slot * 16);
    }
    __syncthreads();
    i32x4 av[4], bv[4];
#pragma unroll
    for (int i = 0; i < 4; ++i) {
      int ra = wm * 64 + i * 16 + (lane & 15);
      av[i] = *(const i32x4*)(As + ra * 64 + (((lane >> 4) ^ (ra & 3)) << 4));
      int rb = wn * 64 + i * 16 + (lane & 15);
      bv[i] = *(const i32x4*)(Bs + rb * 64 + (((lane >> 4) ^ (rb & 3)) << 4));
    }
#pragma unroll
    for (int mi = 0; mi < 4; ++mi)
#pragma unroll
      for (int ni = 0; ni < 4; ++ni)
        acc[mi][ni] = __builtin_amdgcn_mfma_i32_16x16x64_i8(av[mi], bv[ni], acc[mi][ni], 0, 0, 0);
    __syncthreads();
  }
  const int rsub = (lane >> 4) * 4;
  const long row0 = (long)r * 128 + wm * 64;
  const int col00 = c * 128 + wn * 64 + (lane & 15);
  char* base = sc8 + (size_t)z * T_ * M_;
  const float osc = OSCALE_ / (QSCALE_ * KSCALE_);
#pragma unroll
  for (int mi = 0; mi < 4; ++mi)
#pragma unroll
    for (int rg = 0; rg < 4; ++rg) {
      long row = row0 + mi * 16 + rsub + rg;
#pragma unroll
      for (int ni = 0; ni < 4; ++ni) {
        int iv = (int)rintf((float)acc[mi][ni][rg] * osc);
        iv = iv > 127 ? 127 : (iv < -127 ? -127 : iv);
        base[row * (long)M_ + col00 + ni * 16] = (char)iv;
      }
    }
}

// ---------------- postprocess: l2norm q,k; emit outputs + q int8 ----------------
__global__ __launch_bounds__(256) void postproc_kernel(
    const float* __restrict__ qraw, const float* __restrict__ kraw,
    const float* __restrict__ vraw, float* __restrict__ qf,
    u16* __restrict__ qb, u16* __restrict__ kb, char* __restrict__ qi,
    float* __restrict__ kvout) {
  int row = blockIdx.x * 4 + (threadIdx.x >> 6);
  int lane = threadIdx.x & 63;
  size_t rb_ = (size_t)row * C_;
  f32x4 a0 = *(const f32x4*)(qraw + rb_ + lane * 4);
  f32x4 a1 = *(const f32x4*)(qraw + rb_ + 256 + lane * 4);
  float ss = a0[0]*a0[0]+a0[1]*a0[1]+a0[2]*a0[2]+a0[3]*a0[3]
           + a1[0]*a1[0]+a1[1]*a1[1]+a1[2]*a1[2]+a1[3]*a1[3];
#pragma unroll
  for (int m = 1; m < 64; m <<= 1) ss += __shfl_xor(ss, m);
  float rn = 1.0f / fmaxf(sqrtf(ss), 1e-12f);
  f32x4 q0 = a0 * rn, q1 = a1 * rn;
  *(f32x4*)(qf + rb_ + lane * 4) = q0;
  *(f32x4*)(qf + rb_ + 256 + lane * 4) = q1;
  u16x4 t0, t1;
#pragma unroll
  for (int e = 0; e < 4; ++e) { t0[e] = f2bf(q0[e]); t1[e] = f2bf(q1[e]); }
  *(u16x4*)(qb + rb_ + lane * 4) = t0;
  *(u16x4*)(qb + rb_ + 256 + lane * 4) = t1;
  u8x4 i0, i1;
#pragma unroll
  for (int e = 0; e < 4; ++e) { i0[e] = q8(q0[e], QSCALE_); i1[e] = q8(q1[e], QSCALE_); }
  *(u8x4*)((unsigned char*)qi + rb_ + lane * 4) = i0;
  *(u8x4*)((unsigned char*)qi + rb_ + 256 + lane * 4) = i1;
  f32x4 b0 = *(const f32x4*)(kraw + rb_ + lane * 4);
  f32x4 b1 = *(const f32x4*)(kraw + rb_ + 256 + lane * 4);
  float sk = b0[0]*b0[0]+b0[1]*b0[1]+b0[2]*b0[2]+b0[3]*b0[3]
           + b1[0]*b1[0]+b1[1]*b1[1]+b1[2]*b1[2]+b1[3]*b1[3];
#pragma unroll
  for (int m = 1; m < 64; m <<= 1) sk += __shfl_xor(sk, m);
  float rk = 1.0f / fmaxf(sqrtf(sk), 1e-12f);
  f32x4 k0 = b0 * rk, k1 = b1 * rk;
  size_t kvb = (size_t)row * (2 * C_);
  *(f32x4*)(kvout + kvb + lane * 4) = k0;
  *(f32x4*)(kvout + kvb + 256 + lane * 4) = k1;
#pragma unroll
  for (int e = 0; e < 4; ++e) { t0[e] = f2bf(k0[e]); t1[e] = f2bf(k1[e]); }
  *(u16x4*)(kb + rb_ + lane * 4) = t0;
  *(u16x4*)(kb + rb_ + 256 + lane * 4) = t1;
  f32x4 c0 = *(const f32x4*)(vraw + rb_ + lane * 4);
  f32x4 c1 = *(const f32x4*)(vraw + rb_ + 256 + lane * 4);
  *(f32x4*)(kvout + kvb + C_ + lane * 4) = c0;
  *(f32x4*)(kvout + kvb + C_ + 256 + lane * 4) = c1;
}

// ---------------- V transpose -> vT bf16 [b][h][d][t] ----------------
__global__ __launch_bounds__(256) void vtrans_kernel(
    const float* __restrict__ vraw, u16* __restrict__ vT) {
  __shared__ u16 tile[64][65];
  int tt = blockIdx.x, h = blockIdx.y, b = blockIdx.z;
  int tx = threadIdx.x, ty = threadIdx.y;
#pragma unroll
  for (int i = 0; i < 8; ++i) {
    int t = tt * 64 + ty + i * 8;
    const float* src = vraw + (size_t)(b * T_ + t) * C_ + h * 64;
    tile[ty + i * 8][tx] = f2bf(src[tx]);
    tile[ty + i * 8][tx + 32] = f2bf(src[tx + 32]);
  }
  __syncthreads();
#pragma unroll
  for (int i = 0; i < 8; ++i) {
    int d = ty + i * 8;
    u16* dst = vT + ((size_t)((b * H_ + h) * 64 + d)) * T_ + tt * 64;
    dst[tx] = tile[tx][d];
    dst[tx + 32] = tile[tx + 32][d];
  }
}

// ---------------- causal flash attention, 64 q-rows/block (256 blocks) ----------------
__global__ __launch_bounds__(256) void attn_kernel(
    const u16* __restrict__ qb, const u16* __restrict__ kb,
    const u16* __restrict__ vT, float* __restrict__ o) {
  __shared__ __align__(16) u16 Ks[128 * 64];
  __shared__ __align__(16) u16 Vs[64 * 128];
  __shared__ __align__(16) u16 Ps[4][16 * 128];
  int tid = threadIdx.x, lane = tid & 63, w = tid >> 6;
  int it = blockIdx.x, h = blockIdx.y, b = blockIdx.z;
  int t0 = it * 64;
  bf16x8 aq[2];
#pragma unroll
  for (int kk = 0; kk < 2; ++kk) {
    int row = t0 + w * 16 + (lane & 15);
    aq[kk] = *(const bf16x8*)(qb + (size_t)(b * T_ + row) * C_ + h * 64 + kk * 32 + (lane >> 4) * 8);
  }
  f32x4 accO[4];
  float denp[4];
#pragma unroll
  for (int j = 0; j < 4; ++j) { accO[j] = f32x4{0.f,0.f,0.f,0.f}; denp[j] = 0.f; }

  int ntiles = it / 2 + 1;
  for (int jt = 0; jt < ntiles; ++jt) {
    int j0 = jt * 128;
#pragma unroll
    for (int i2 = 0; i2 < 4; ++i2) {
      int slot = i2 * 256 + tid;
      int rr = slot >> 3, ssw = slot & 7;
      int q = ssw ^ (rr & 7);
      gl_lds16(kb + (size_t)(b * T_ + j0 + rr) * C_ + h * 64 + q * 8, (char*)Ks + slot * 16);
    }
#pragma unroll
    for (int i2 = 0; i2 < 4; ++i2) {
      int slot = i2 * 256 + tid;
      int rr = slot >> 4, ssw = slot & 15;
      int q = ssw ^ (rr & 15);
      gl_lds16(vT + ((size_t)((b * H_ + h) * 64 + rr)) * T_ + j0 + q * 8, (char*)Vs + slot * 16);
    }
    __syncthreads();
    f32x4 s[8];
#pragma unroll
    for (int ni = 0; ni < 8; ++ni) s[ni] = f32x4{0.f,0.f,0.f,0.f};
#pragma unroll
    for (int kk = 0; kk < 2; ++kk) {
      bf16x8 bk[8];
#pragma unroll
      for (int ni = 0; ni < 8; ++ni) {
        int rbi = ni * 16 + (lane & 15);
        int blk = kk * 4 + (lane >> 4);
        bk[ni] = *(const bf16x8*)((const char*)Ks + rbi * 128 + ((blk ^ (rbi & 7)) << 4));
      }
#pragma unroll
      for (int ni = 0; ni < 8; ++ni)
        s[ni] = __builtin_amdgcn_mfma_f32_16x16x32_bf16(aq[kk], bk[ni], s[ni], 0, 0, 0);
    }
#pragma unroll
    for (int ni = 0; ni < 8; ++ni)
#pragma unroll
      for (int rg = 0; rg < 4; ++rg) {
        int qrow = t0 + w * 16 + (lane >> 4) * 4 + rg;
        int kvcol = j0 + ni * 16 + (lane & 15);
        float sv = s[ni][rg] * SCALE_;
        float p = (kvcol <= qrow) ? __expf(sv) : 0.0f;
        denp[rg] += p;
        int qk = (lane >> 4) * 4 + rg;
        int kvl = ni * 16 + (lane & 15);
        int blk2 = kvl >> 3;
        *(u16*)((char*)Ps[w] + qk * 256 + ((blk2 ^ qk) << 4) + (kvl & 7) * 2) = f2bf(p);
      }
#pragma unroll
    for (int kk2 = 0; kk2 < 4; ++kk2) {
      bf16x8 ap, bvv[4];
      int blk = kk2 * 4 + (lane >> 4);
      int rq = lane & 15;
      ap = *(const bf16x8*)((const char*)Ps[w] + rq * 256 + ((blk ^ rq) << 4));
#pragma unroll
      for (int nd = 0; nd < 4; ++nd) {
        int rd = nd * 16 + (lane & 15);
        bvv[nd] = *(const bf16x8*)((const char*)Vs + rd * 256 + ((blk ^ (rd & 15)) << 4));
      }
#pragma unroll
      for (int nd = 0; nd < 4; ++nd)
        accO[nd] = __builtin_amdgcn_mfma_f32_16x16x32_bf16(ap, bvv[nd], accO[nd], 0, 0, 0);
    }
    __syncthreads();
  }
  float den[4];
#pragma unroll
  for (int rg = 0; rg < 4; ++rg) {
    float d = denp[rg];
    d += __shfl_xor(d, 1); d += __shfl_xor(d, 2);
    d += __shfl_xor(d, 4); d += __shfl_xor(d, 8);
    den[rg] = d;
  }
#pragma unroll
  for (int nd = 0; nd < 4; ++nd)
#pragma unroll
    for (int rg = 0; rg < 4; ++rg) {
      int row = t0 + w * 16 + (lane >> 4) * 4 + rg;
      int d = nd * 16 + (lane & 15);
      o[(size_t)(b * T_ + row) * C_ + h * 64 + d] = accO[nd][rg] / den[rg];
    }
}

// ---------------- fused: approx top-64 (wave-local extraction) -> exact rescore ->
//                  top-32 -> mem attention -> combine ----------------
__global__ __launch_bounds__(256) void topk_tail_kernel(
    const char* __restrict__ scores, const float* __restrict__ qf,
    const float* __restrict__ mem, const float* __restrict__ attn,
    const float* __restrict__ gate, u16* __restrict__ comb) {
  int row = blockIdx.x, b = row >> 10;
  int tid = threadIdx.x, lane = tid & 63, w = tid >> 6;
  __shared__ unsigned candKey[256];
  __shared__ float qL[512];
  __shared__ float sL[NCAND_];
  __shared__ float sHh[NCAND_][8];
  __shared__ int cL[NCAND_];
  __shared__ int wIdx[TOPK_];
  __shared__ float eL[TOPK_][8];
  // load q while scanning scores
  qL[tid] = qf[(size_t)row * C_ + tid];
  qL[256 + tid] = qf[(size_t)row * C_ + 256 + tid];
  // phase 0: per-thread top-8 over 128 int8 scores
  const unsigned char* s = (const unsigned char*)scores + (size_t)row * M_;
  unsigned c[8];
#pragma unroll
  for (int i = 0; i < 8; ++i) c[i] = 0;
  for (int i2 = 0; i2 < 16; ++i2) {
    int base = i2 * 2048 + tid * 8;
    uint2 v = *(const uint2*)(s + base);
#pragma unroll
    for (int e = 0; e < 8; ++e) {
      unsigned byte = (e < 4) ? ((v.x >> (8 * e)) & 0xFF) : ((v.y >> (8 * (e - 4))) & 0xFF);
      unsigned key = byte ^ 0x80u;
      unsigned cmb = (key << 15) | (unsigned)(32767 - (base + e));
      if (cmb > c[7]) {
        c[7] = cmb;
#pragma unroll
        for (int ss = 7; ss > 0; --ss) {
          if (c[ss] > c[ss - 1]) { unsigned t = c[ss - 1]; c[ss - 1] = c[ss]; c[ss] = t; }
        }
      }
    }
  }
  // phase 1: wave-local top-64 extraction (no barriers; butterfly max each round)
  for (int r = 0; r < 64; ++r) {
    unsigned bb = c[0];
#pragma unroll
    for (int m = 1; m < 64; m <<= 1) {
      unsigned o = __shfl_xor(bb, m);
      bb = (o > bb) ? o : bb;
    }
    if (lane == 0) candKey[w * 64 + r] = bb;
    if (c[0] == bb) {
#pragma unroll
      for (int ss = 0; ss < 7; ++ss) c[ss] = c[ss + 1];
      c[7] = 0;
    }
  }
  __syncthreads();
  // phase 2: merge 4x64 -> block top-64 by rank (keys unique)
  {
    unsigned my = candKey[tid];
    int rank = 0;
    for (int j = 0; j < 256; ++j) rank += (candKey[j] > my);
    if (rank < NCAND_) cL[rank] = 32767 - (int)(my & 32767u);
  }
  __syncthreads();
  // phase 3: exact f32 rescore of 64 candidates, 16 per wave
#pragma unroll 4
  for (int i = 0; i < 16; ++i) {
    int cdx = w * 16 + i;
    const float* mrow = mem + ((size_t)(b * M_ + cL[cdx])) * 1024;
    f32x4 k0 = *(const f32x4*)(mrow + lane * 8);
    f32x4 k1 = *(const f32x4*)(mrow + lane * 8 + 4);
    float p = qL[lane*8+0]*k0[0] + qL[lane*8+1]*k0[1] + qL[lane*8+2]*k0[2] + qL[lane*8+3]*k0[3]
            + qL[lane*8+4]*k1[0] + qL[lane*8+5]*k1[1] + qL[lane*8+6]*k1[2] + qL[lane*8+7]*k1[3];
    p += __shfl_xor(p, 1); p += __shfl_xor(p, 2); p += __shfl_xor(p, 4);
    if ((lane & 7) == 0) sHh[cdx][lane >> 3] = p;
    float pf = p;
    pf += __shfl_xor(pf, 8); pf += __shfl_xor(pf, 16); pf += __shfl_xor(pf, 32);
    if (lane == 0) sL[cdx] = pf;
  }
  __syncthreads();
  // phase 4: exact ranking (score desc, index asc)
  if (tid < NCAND_) {
    float sv = sL[tid]; int id = cL[tid];
    int rank = 0;
#pragma unroll
    for (int j = 0; j < NCAND_; ++j) {
      float sj = sL[j];
      rank += (sj > sv) || (sj == sv && cL[j] < id);
    }
    if (rank < TOPK_) {
      wIdx[rank] = id;
#pragma unroll
      for (int h = 0; h < 8; ++h)
        eL[rank][h] = __expf(sHh[tid][h] * SCALE_);
    }
  }
  __syncthreads();
  // phase 5: gather v of winners, weighted sum, combine with causal attn
  int h2 = tid >> 5, dp = tid & 31;
  float num0 = 0.f, num1 = 0.f, den = 0.f;
#pragma unroll 8
  for (int k = 0; k < TOPK_; ++k) {
    float wgt = eL[k][h2];
    const float* vrow = mem + ((size_t)(b * M_ + wIdx[k])) * 1024 + 512;
    f32x2 vv = *(const f32x2*)(vrow + h2 * 64 + dp * 2);
    num0 += wgt * vv[0];
    num1 += wgt * vv[1];
    den += wgt;
  }
  float g = gate[h2];
  int c0 = h2 * 64 + dp * 2;
  float a0 = attn[(size_t)row * C_ + c0];
  float a1 = attn[(size_t)row * C_ + c0 + 1];
  u16 o0 = f2bf(g * (num0 / den) + (1.0f - g) * a0);
  u16 o1 = f2bf(g * (num1 / den) + (1.0f - g) * a1);
  *(unsigned*)(comb + (size_t)row * C_ + c0) = (unsigned)o0 | ((unsigned)o1 << 16);
}

extern "C" void kernel_launch(void* const* d_in, const int* in_sizes, int n_in,
                              void* d_out, int out_size, void* d_ws, size_t ws_size,
                              hipStream_t stream) {
  const float* x    = (const float*)d_in[0];
  const float* mem  = (const float*)d_in[1];
  const float* lnw  = (const float*)d_in[2];
  const float* lnb  = (const float*)d_in[3];
  const float* Wq   = (const float*)d_in[4];
  const float* bq   = (const float*)d_in[5];
  const float* Wk   = (const float*)d_in[6];
  const float* bk   = (const float*)d_in[7];
  const float* Wv   = (const float*)d_in[8];
  const float* bv   = (const float*)d_in[9];
  const float* Wo   = (const float*)d_in[10];
  const float* bo   = (const float*)d_in[11];
  const float* gate = (const float*)d_in[12];
  float* out   = (float*)d_out;
  float* kvout = out + (size_t)B_ * T_ * C_;

  size_t off = 0;
  auto alloc = [&](size_t bytes) {
    char* r = (char*)d_ws + off;
    off += (bytes + 255) & ~(size_t)255;
    return r;
  };
  u16*      WT   = (u16*)alloc(3ull * C_ * C_ * 2);
  char*     ki   = (char*)alloc((size_t)B_ * M_ * C_);
  u16*      xn   = (u16*)alloc((size_t)B_ * T_ * C_ * 2);
  float*    xnf  = (float*)alloc((size_t)B_ * T_ * C_ * 4);
  float*    qraw = (float*)alloc((size_t)B_ * T_ * C_ * 4);
  float*    kvraw= (float*)alloc(2ull * B_ * T_ * C_ * 4);
  float*    kraw = kvraw;
  float*    vraw = kvraw + (size_t)B_ * T_ * C_;
  float*    qf   = (float*)alloc((size_t)B_ * T_ * C_ * 4);
  u16*      qb   = (u16*)alloc((size_t)B_ * T_ * C_ * 2);
  u16*      kb   = (u16*)alloc((size_t)B_ * T_ * C_ * 2);
  char*     qi   = (char*)alloc((size_t)B_ * T_ * C_);
  u16*      vT   = (u16*)alloc((size_t)B_ * T_ * C_ * 2);
  float*    attn = (float*)alloc((size_t)B_ * T_ * C_ * 4);
  char*     sc8  = (char*)alloc((size_t)B_ * T_ * M_);
  u16*      comb = (u16*)alloc((size_t)B_ * T_ * C_ * 2);
  if (off > ws_size) return;

  wtrans_kernel<<<dim3(16, 16, 3), dim3(32, 8), 0, stream>>>(Wk, Wv, Wo, WT);
  prep_keys_kernel<<<8192, 256, 0, stream>>>(mem, ki);
  ln_kernel<<<512, 256, 0, stream>>>(x, lnw, lnb, xn, xnf);
  gemm_f32<<<dim3(32, 8), 256, 0, stream>>>(xnf, Wq, bq, qraw);
  gemm128<<<dim3(16, 4, 2), 256, 0, stream>>>(xn, 0, WT, (long)C_ * C_,
                                              kvraw, (long)B_ * T_ * C_, bk, bv, C_);
  postproc_kernel<<<512, 256, 0, stream>>>(qraw, kraw, vraw, qf, qb, kb, qi, kvout);
  vtrans_kernel<<<dim3(16, 8, 2), dim3(32, 8), 0, stream>>>(vraw, vT);
  attn_kernel<<<dim3(16, 8, 2), 256, 0, stream>>>(qb, kb, vT, attn);
  gemm_sc8<<<4096, 256, 0, stream>>>(qi, ki, sc8);
  topk_tail_kernel<<<2048, 256, 0, stream>>>(sc8, qf, mem, attn, gate, comb);
  gemm128<<<dim3(16, 4, 1), 256, 0, stream>>>(comb, 0, WT + 2 * C_ * C_, 0,
                                              out, 0, bo, nullptr, C_);
}

// Round 10
// 324.832 us; speedup vs baseline: 1.0948x; 1.0046x over previous
//
#include <hip/hip_runtime.h>
#include <hip/hip_bf16.h>

#define B_ 2
#define T_ 1024
#define H_ 8
#define D_ 64
#define C_ 512
#define M_ 32768
#define TOPK_ 32
#define NCAND_ 64
#define SCALE_ 0.125f
#define QSCALE_ 360.0f
#define KSCALE_ 24.0f
#define OSCALE_ 20.0f

typedef unsigned short u16;
typedef float    f32x2  __attribute__((ext_vector_type(2)));
typedef float    f32x4  __attribute__((ext_vector_type(4)));
typedef __bf16   bf16x8 __attribute__((ext_vector_type(8)));
typedef u16      u16x4  __attribute__((ext_vector_type(4)));
typedef int      i32x4  __attribute__((ext_vector_type(4)));
typedef unsigned char u8x4 __attribute__((ext_vector_type(4)));

__device__ __forceinline__ u16 f2bf(float f) {
  __hip_bfloat16 b = __float2bfloat16(f);
  u16 u; __builtin_memcpy(&u, &b, 2); return u;
}

__device__ __forceinline__ unsigned char q8(float v, float scale) {
  int iv = (int)rintf(v * scale);
  iv = iv > 127 ? 127 : (iv < -127 ? -127 : iv);
  return (unsigned char)(signed char)iv;
}

__device__ __forceinline__ void gl_lds16(const void* g, void* l) {
  __builtin_amdgcn_global_load_lds(
      (const __attribute__((address_space(1))) void*)g,
      (__attribute__((address_space(3))) void*)l, 16, 0, 0);
}

// ---------------- weight transpose: W[k][n] f32 -> WT[n][k] bf16 (Wk,Wv,Wo) ----------------
__global__ __launch_bounds__(256) void wtrans_kernel(
    const float* __restrict__ W0, const float* __restrict__ W1,
    const float* __restrict__ W2, u16* __restrict__ WT) {
  __shared__ u16 tl[32][33];
  int z = blockIdx.z;
  const float* W = (z == 0) ? W0 : (z == 1) ? W1 : W2;
  u16* dst = WT + (size_t)z * C_ * C_;
  int n0 = blockIdx.x * 32, k0 = blockIdx.y * 32;
  int tx = threadIdx.x, ty = threadIdx.y;
#pragma unroll
  for (int i = 0; i < 4; ++i) {
    int k = k0 + ty + i * 8;
    tl[ty + i * 8][tx] = f2bf(W[(size_t)k * C_ + n0 + tx]);
  }
  __syncthreads();
#pragma unroll
  for (int i = 0; i < 4; ++i) {
    int nn = ty + i * 8;
    dst[(size_t)(n0 + nn) * C_ + k0 + tx] = tl[tx][nn];
  }
}

// ---------------- keys f32 (strided in memory_kv) -> int8 [b][m][c], scale 24 ----------------
__global__ __launch_bounds__(256) void prep_keys_kernel(
    const float* __restrict__ mem, char* __restrict__ ki) {
  const int n4 = B_ * M_ * C_ / 4;
  for (int i = blockIdx.x * 256 + threadIdx.x; i < n4; i += gridDim.x * 256) {
    int row = i >> 7;
    int c4 = i & 127;
    f32x4 v = *(const f32x4*)(mem + ((size_t)row * 1024) + c4 * 4);
    u8x4 o;
    o[0] = q8(v[0], KSCALE_); o[1] = q8(v[1], KSCALE_);
    o[2] = q8(v[2], KSCALE_); o[3] = q8(v[3], KSCALE_);
    *(u8x4*)((unsigned char*)ki + (size_t)i * 4) = o;
  }
}

// ---------------- layernorm: x f32 -> xn bf16 + xnf f32 ----------------
__global__ __launch_bounds__(256) void ln_kernel(
    const float* __restrict__ x, const float* __restrict__ w,
    const float* __restrict__ bia, u16* __restrict__ xn, float* __restrict__ xnf) {
  int row = blockIdx.x * 4 + (threadIdx.x >> 6);
  int lane = threadIdx.x & 63;
  const float* xr = x + (size_t)row * C_;
  f32x4 v0 = *(const f32x4*)(xr + lane * 4);
  f32x4 v1 = *(const f32x4*)(xr + 256 + lane * 4);
  float s = v0[0] + v0[1] + v0[2] + v0[3] + v1[0] + v1[1] + v1[2] + v1[3];
  float q = v0[0]*v0[0]+v0[1]*v0[1]+v0[2]*v0[2]+v0[3]*v0[3]
          + v1[0]*v1[0]+v1[1]*v1[1]+v1[2]*v1[2]+v1[3]*v1[3];
#pragma unroll
  for (int m = 1; m < 64; m <<= 1) { s += __shfl_xor(s, m); q += __shfl_xor(q, m); }
  float mean = s * (1.0f / C_);
  float var  = q * (1.0f / C_) - mean * mean;
  float rs = rsqrtf(var + 1e-5f);
  u16x4 o0, o1;
  f32x4 f0, f1;
#pragma unroll
  for (int e = 0; e < 4; ++e) {
    int c = lane * 4 + e;
    f0[e] = (v0[e] - mean) * rs * w[c] + bia[c];
    o0[e] = f2bf(f0[e]);
    int c2 = 256 + lane * 4 + e;
    f1[e] = (v1[e] - mean) * rs * w[c2] + bia[c2];
    o1[e] = f2bf(f1[e]);
  }
  *(u16x4*)(xn + (size_t)row * C_ + lane * 4) = o0;
  *(u16x4*)(xn + (size_t)row * C_ + 256 + lane * 4) = o1;
  *(f32x4*)(xnf + (size_t)row * C_ + lane * 4) = f0;
  *(f32x4*)(xnf + (size_t)row * C_ + 256 + lane * 4) = f1;
}

// ---------------- exact f32 GEMM (for q): C = A(2048x512) * Bw(512x512) + bias ----------------
__global__ __launch_bounds__(256) void gemm_f32(
    const float* __restrict__ A, const float* __restrict__ Bw,
    const float* __restrict__ bias, float* __restrict__ Cout) {
  __shared__ float As[64][33];
  __shared__ float Bs[32][64];
  int tid = threadIdx.x;
  int tx = tid & 15, ty = tid >> 4;
  int r0 = blockIdx.x * 64, c0 = blockIdx.y * 64;
  f32x4 acc[4];
#pragma unroll
  for (int i = 0; i < 4; ++i) acc[i] = f32x4{0.f, 0.f, 0.f, 0.f};
  for (int kt = 0; kt < 16; ++kt) {
    int k0 = kt * 32;
#pragma unroll
    for (int i2 = 0; i2 < 2; ++i2) {
      int idx = i2 * 256 + tid;
      int arow = idx >> 3, ac = idx & 7;
      f32x4 av = *(const f32x4*)(A + (size_t)(r0 + arow) * 512 + k0 + ac * 4);
      As[arow][ac * 4 + 0] = av[0]; As[arow][ac * 4 + 1] = av[1];
      As[arow][ac * 4 + 2] = av[2]; As[arow][ac * 4 + 3] = av[3];
      int krow = idx >> 4, cc = idx & 15;
      f32x4 bv = *(const f32x4*)(Bw + (size_t)(k0 + krow) * 512 + c0 + cc * 4);
      *(f32x4*)(&Bs[krow][cc * 4]) = bv;
    }
    __syncthreads();
#pragma unroll
    for (int kk = 0; kk < 32; ++kk) {
      f32x4 bv = *(const f32x4*)(&Bs[kk][tx * 4]);
#pragma unroll
      for (int i = 0; i < 4; ++i) {
        float av = As[ty * 4 + i][kk];
        acc[i] += av * bv;
      }
    }
    __syncthreads();
  }
  f32x4 bb = *(const f32x4*)(bias + c0 + tx * 4);
#pragma unroll
  for (int i = 0; i < 4; ++i)
    *(f32x4*)(Cout + (size_t)(r0 + ty * 4 + i) * 512 + c0 + tx * 4) = acc[i] + bb;
}

// ---------------- generic 128x128 bf16 MFMA GEMM (f32 out + bias; z selects bias/bias2) -------
__global__ __launch_bounds__(256) void gemm128(
    const u16* __restrict__ A, long aBS,
    const u16* __restrict__ Bt, long bBS,
    float* __restrict__ Cf, long cBS,
    const float* __restrict__ bias, const float* __restrict__ bias2, int ldc) {
  __shared__ __align__(16) u16 As[128 * 64];
  __shared__ __align__(16) u16 Bs[128 * 64];
  const int tid = threadIdx.x;
  const int lane = tid & 63, w = tid >> 6;
  const int wm = w >> 1, wn = w & 1;
  const int z = blockIdx.z;
  const u16* Ab = A + (size_t)z * aBS + (size_t)blockIdx.x * 128 * 512;
  const u16* Bb = Bt + (size_t)z * bBS + (size_t)blockIdx.y * 128 * 512;

  f32x4 acc[4][4];
#pragma unroll
  for (int i = 0; i < 4; ++i)
#pragma unroll
    for (int j = 0; j < 4; ++j) acc[i][j] = f32x4{0.f, 0.f, 0.f, 0.f};

  for (int kt = 0; kt < 8; ++kt) {
    const u16* Akt = Ab + kt * 64;
    const u16* Bkt = Bb + kt * 64;
#pragma unroll
    for (int it = 0; it < 4; ++it) {
      int slot = it * 256 + tid;
      int rr = slot >> 3, ss = slot & 7;
      int q = ss ^ (rr & 7);
      gl_lds16(Akt + (size_t)rr * 512 + q * 8, (char*)As + slot * 16);
      gl_lds16(Bkt + (size_t)rr * 512 + q * 8, (char*)Bs + slot * 16);
    }
    __syncthreads();
#pragma unroll
    for (int kk = 0; kk < 2; ++kk) {
      bf16x8 av[4], bv[4];
#pragma unroll
      for (int i = 0; i < 4; ++i) {
        int blk = kk * 4 + (lane >> 4);
        int ra = wm * 64 + i * 16 + (lane & 15);
        av[i] = *(const bf16x8*)((const char*)As + ra * 128 + ((blk ^ (ra & 7)) << 4));
        int rb = wn * 64 + i * 16 + (lane & 15);
        bv[i] = *(const bf16x8*)((const char*)Bs + rb * 128 + ((blk ^ (rb & 7)) << 4));
      }
#pragma unroll
      for (int mi = 0; mi < 4; ++mi)
#pragma unroll
        for (int ni = 0; ni < 4; ++ni)
          acc[mi][ni] = __builtin_amdgcn_mfma_f32_16x16x32_bf16(av[mi], bv[ni], acc[mi][ni], 0, 0, 0);
    }
    __syncthreads();
  }
  const float* bi = (z == 1 && bias2) ? bias2 : bias;
  const long cbase = (long)z * cBS;
  const int rsub = (lane >> 4) * 4;
  const long row0 = (long)blockIdx.x * 128 + wm * 64;
  const int col00 = wn * 64 + (lane & 15) + (int)blockIdx.y * 128;
#pragma unroll
  for (int mi = 0; mi < 4; ++mi)
#pragma unroll
    for (int rg = 0; rg < 4; ++rg) {
      long row = row0 + mi * 16 + rsub + rg;
#pragma unroll
      for (int ni = 0; ni < 4; ++ni) {
        int col = col00 + ni * 16;
        float bb = bi ? bi[col] : 0.0f;
        Cf[cbase + row * (long)ldc + col] = acc[mi][ni][rg] + bb;
      }
    }
}

// ---------------- postprocess: l2norm q,k; emit outputs + q int8 ----------------
__global__ __launch_bounds__(256) void postproc_kernel(
    const float* __restrict__ qraw, const float* __restrict__ kraw,
    const float* __restrict__ vraw, float* __restrict__ qf,
    u16* __restrict__ qb, u16* __restrict__ kb, char* __restrict__ qi,
    float* __restrict__ kvout) {
  int row = blockIdx.x * 4 + (threadIdx.x >> 6);
  int lane = threadIdx.x & 63;
  size_t rb_ = (size_t)row * C_;
  f32x4 a0 = *(const f32x4*)(qraw + rb_ + lane * 4);
  f32x4 a1 = *(const f32x4*)(qraw + rb_ + 256 + lane * 4);
  float ss = a0[0]*a0[0]+a0[1]*a0[1]+a0[2]*a0[2]+a0[3]*a0[3]
           + a1[0]*a1[0]+a1[1]*a1[1]+a1[2]*a1[2]+a1[3]*a1[3];
#pragma unroll
  for (int m = 1; m < 64; m <<= 1) ss += __shfl_xor(ss, m);
  float rn = 1.0f / fmaxf(sqrtf(ss), 1e-12f);
  f32x4 q0 = a0 * rn, q1 = a1 * rn;
  *(f32x4*)(qf + rb_ + lane * 4) = q0;
  *(f32x4*)(qf + rb_ + 256 + lane * 4) = q1;
  u16x4 t0, t1;
#pragma unroll
  for (int e = 0; e < 4; ++e) { t0[e] = f2bf(q0[e]); t1[e] = f2bf(q1[e]); }
  *(u16x4*)(qb + rb_ + lane * 4) = t0;
  *(u16x4*)(qb + rb_ + 256 + lane * 4) = t1;
  u8x4 i0, i1;
#pragma unroll
  for (int e = 0; e < 4; ++e) { i0[e] = q8(q0[e], QSCALE_); i1[e] = q8(q1[e], QSCALE_); }
  *(u8x4*)((unsigned char*)qi + rb_ + lane * 4) = i0;
  *(u8x4*)((unsigned char*)qi + rb_ + 256 + lane * 4) = i1;
  f32x4 b0 = *(const f32x4*)(kraw + rb_ + lane * 4);
  f32x4 b1 = *(const f32x4*)(kraw + rb_ + 256 + lane * 4);
  float sk = b0[0]*b0[0]+b0[1]*b0[1]+b0[2]*b0[2]+b0[3]*b0[3]
           + b1[0]*b1[0]+b1[1]*b1[1]+b1[2]*b1[2]+b1[3]*b1[3];
#pragma unroll
  for (int m = 1; m < 64; m <<= 1) sk += __shfl_xor(sk, m);
  float rk = 1.0f / fmaxf(sqrtf(sk), 1e-12f);
  f32x4 k0 = b0 * rk, k1 = b1 * rk;
  size_t kvb = (size_t)row * (2 * C_);
  *(f32x4*)(kvout + kvb + lane * 4) = k0;
  *(f32x4*)(kvout + kvb + 256 + lane * 4) = k1;
#pragma unroll
  for (int e = 0; e < 4; ++e) { t0[e] = f2bf(k0[e]); t1[e] = f2bf(k1[e]); }
  *(u16x4*)(kb + rb_ + lane * 4) = t0;
  *(u16x4*)(kb + rb_ + 256 + lane * 4) = t1;
  f32x4 c0 = *(const f32x4*)(vraw + rb_ + lane * 4);
  f32x4 c1 = *(const f32x4*)(vraw + rb_ + 256 + lane * 4);
  *(f32x4*)(kvout + kvb + C_ + lane * 4) = c0;
  *(f32x4*)(kvout + kvb + C_ + 256 + lane * 4) = c1;
}

// ---------------- V transpose -> vT bf16 [b][h][d][t] ----------------
__global__ __launch_bounds__(256) void vtrans_kernel(
    const float* __restrict__ vraw, u16* __restrict__ vT) {
  __shared__ u16 tile[64][65];
  int tt = blockIdx.x, h = blockIdx.y, b = blockIdx.z;
  int tx = threadIdx.x, ty = threadIdx.y;
#pragma unroll
  for (int i = 0; i < 8; ++i) {
    int t = tt * 64 + ty + i * 8;
    const float* src = vraw + (size_t)(b * T_ + t) * C_ + h * 64;
    tile[ty + i * 8][tx] = f2bf(src[tx]);
    tile[ty + i * 8][tx + 32] = f2bf(src[tx + 32]);
  }
  __syncthreads();
#pragma unroll
  for (int i = 0; i < 8; ++i) {
    int d = ty + i * 8;
    u16* dst = vT + ((size_t)((b * H_ + h) * 64 + d)) * T_ + tt * 64;
    dst[tx] = tile[tx][d];
    dst[tx + 32] = tile[tx + 32][d];
  }
}

// ======== fused L4: causal flash attention (256 blocks) + int8 scores GEMM (4096 blocks) ======
// attn feeds only the bf16-tolerant output path; sc8 is integer-exact (i8 MFMA + one f32 mul
// + rintf on int < 2^24) — both provably robust to co-compilation codegen perturbation.

__device__ __forceinline__ void attn_body(char* pool, int p,
    const u16* __restrict__ qb, const u16* __restrict__ kb,
    const u16* __restrict__ vT, float* __restrict__ o) {
  u16* Ks = (u16*)pool;                 // [128*64]
  u16* Vs = (u16*)(pool + 16384);       // [64*128]
  char* PsBase = pool + 32768;          // [4][16*128] u16
  int tid = threadIdx.x, lane = tid & 63, w = tid >> 6;
  int it = p & 15, h = (p >> 4) & 7, b = p >> 7;
  char* PsW = PsBase + w * 4096;
  int t0 = it * 64;
  bf16x8 aq[2];
#pragma unroll
  for (int kk = 0; kk < 2; ++kk) {
    int row = t0 + w * 16 + (lane & 15);
    aq[kk] = *(const bf16x8*)(qb + (size_t)(b * T_ + row) * C_ + h * 64 + kk * 32 + (lane >> 4) * 8);
  }
  f32x4 accO[4];
  float denp[4];
#pragma unroll
  for (int j = 0; j < 4; ++j) { accO[j] = f32x4{0.f,0.f,0.f,0.f}; denp[j] = 0.f; }

  int ntiles = it / 2 + 1;
  for (int jt = 0; jt < ntiles; ++jt) {
    int j0 = jt * 128;
#pragma unroll
    for (int i2 = 0; i2 < 4; ++i2) {
      int slot = i2 * 256 + tid;
      int rr = slot >> 3, ssw = slot & 7;
      int q = ssw ^ (rr & 7);
      gl_lds16(kb + (size_t)(b * T_ + j0 + rr) * C_ + h * 64 + q * 8, (char*)Ks + slot * 16);
    }
#pragma unroll
    for (int i2 = 0; i2 < 4; ++i2) {
      int slot = i2 * 256 + tid;
      int rr = slot >> 4, ssw = slot & 15;
      int q = ssw ^ (rr & 15);
      gl_lds16(vT + ((size_t)((b * H_ + h) * 64 + rr)) * T_ + j0 + q * 8, (char*)Vs + slot * 16);
    }
    __syncthreads();
    f32x4 s[8];
#pragma unroll
    for (int ni = 0; ni < 8; ++ni) s[ni] = f32x4{0.f,0.f,0.f,0.f};
#pragma unroll
    for (int kk = 0; kk < 2; ++kk) {
      bf16x8 bk[8];
#pragma unroll
      for (int ni = 0; ni < 8; ++ni) {
        int rbi = ni * 16 + (lane & 15);
        int blk = kk * 4 + (lane >> 4);
        bk[ni] = *(const bf16x8*)((const char*)Ks + rbi * 128 + ((blk ^ (rbi & 7)) << 4));
      }
#pragma unroll
      for (int ni = 0; ni < 8; ++ni)
        s[ni] = __builtin_amdgcn_mfma_f32_16x16x32_bf16(aq[kk], bk[ni], s[ni], 0, 0, 0);
    }
#pragma unroll
    for (int ni = 0; ni < 8; ++ni)
#pragma unroll
      for (int rg = 0; rg < 4; ++rg) {
        int qrow = t0 + w * 16 + (lane >> 4) * 4 + rg;
        int kvcol = j0 + ni * 16 + (lane & 15);
        float sv = s[ni][rg] * SCALE_;
        float pp = (kvcol <= qrow) ? __expf(sv) : 0.0f;
        denp[rg] += pp;
        int qk = (lane >> 4) * 4 + rg;
        int kvl = ni * 16 + (lane & 15);
        int blk2 = kvl >> 3;
        *(u16*)(PsW + qk * 256 + ((blk2 ^ qk) << 4) + (kvl & 7) * 2) = f2bf(pp);
      }
#pragma unroll
    for (int kk2 = 0; kk2 < 4; ++kk2) {
      bf16x8 ap, bvv[4];
      int blk = kk2 * 4 + (lane >> 4);
      int rq = lane & 15;
      ap = *(const bf16x8*)(PsW + rq * 256 + ((blk ^ rq) << 4));
#pragma unroll
      for (int nd = 0; nd < 4; ++nd) {
        int rd = nd * 16 + (lane & 15);
        bvv[nd] = *(const bf16x8*)((const char*)Vs + rd * 256 + ((blk ^ (rd & 15)) << 4));
      }
#pragma unroll
      for (int nd = 0; nd < 4; ++nd)
        accO[nd] = __builtin_amdgcn_mfma_f32_16x16x32_bf16(ap, bvv[nd], accO[nd], 0, 0, 0);
    }
    __syncthreads();
  }
  float den[4];
#pragma unroll
  for (int rg = 0; rg < 4; ++rg) {
    float d = denp[rg];
    d += __shfl_xor(d, 1); d += __shfl_xor(d, 2);
    d += __shfl_xor(d, 4); d += __shfl_xor(d, 8);
    den[rg] = d;
  }
#pragma unroll
  for (int nd = 0; nd < 4; ++nd)
#pragma unroll
    for (int rg = 0; rg < 4; ++rg) {
      int row = t0 + w * 16 + (lane >> 4) * 4 + rg;
      int d = nd * 16 + (lane & 15);
      o[(size_t)(b * T_ + row) * C_ + h * 64 + d] = accO[nd][rg] / den[rg];
    }
}

__device__ __forceinline__ void sc8_body(char* pool, int p,
    const char* __restrict__ A, const char* __restrict__ Bt, char* __restrict__ sc8) {
  char* As = pool;
  char* Bs = pool + 8192;
  const int tid = threadIdx.x;
  const int lane = tid & 63, w = tid >> 6;
  const int wm = w >> 1, wn = w & 1;
  const int z = p >> 11;
  const int q_ = p & 2047;
  const int r = (q_ >> 3) & 7;
  const int c = ((q_ >> 6) << 3) | (q_ & 7);
  const char* Ab = A + (size_t)z * T_ * C_ + (size_t)r * 128 * 512;
  const char* Bb = Bt + (size_t)z * M_ * C_ + (size_t)c * 128 * 512;

  i32x4 acc[4][4];
#pragma unroll
  for (int i = 0; i < 4; ++i)
#pragma unroll
    for (int j = 0; j < 4; ++j) acc[i][j] = i32x4{0, 0, 0, 0};

  for (int kt = 0; kt < 8; ++kt) {
    const char* Akt = Ab + kt * 64;
    const char* Bkt = Bb + kt * 64;
#pragma unroll
    for (int it = 0; it < 2; ++it) {
      int slot = it * 256 + tid;
      int rr = slot >> 2, cw = slot & 3;
      int ch = cw ^ (rr & 3);
      gl_lds16(Akt + (size_t)rr * 512 + ch * 16, As + slot * 16);
      gl_lds16(Bkt + (size_t)rr * 512 + ch * 16, Bs + slot * 16);
    }
    __syncthreads();
    i32x4 av[4], bv[4];
#pragma unroll
    for (int i = 0; i < 4; ++i) {
      int ra = wm * 64 + i * 16 + (lane & 15);
      av[i] = *(const i32x4*)(As + ra * 64 + (((lane >> 4) ^ (ra & 3)) << 4));
      int rb = wn * 64 + i * 16 + (lane & 15);
      bv[i] = *(const i32x4*)(Bs + rb * 64 + (((lane >> 4) ^ (rb & 3)) << 4));
    }
#pragma unroll
    for (int mi = 0; mi < 4; ++mi)
#pragma unroll
      for (int ni = 0; ni < 4; ++ni)
        acc[mi][ni] = __builtin_amdgcn_mfma_i32_16x16x64_i8(av[mi], bv[ni], acc[mi][ni], 0, 0, 0);
    __syncthreads();
  }
  const int rsub = (lane >> 4) * 4;
  const long row0 = (long)r * 128 + wm * 64;
  const int col00 = c * 128 + wn * 64 + (lane & 15);
  char* base = sc8 + (size_t)z * T_ * M_;
  const float osc = OSCALE_ / (QSCALE_ * KSCALE_);
#pragma unroll
  for (int mi = 0; mi < 4; ++mi)
#pragma unroll
    for (int rg = 0; rg < 4; ++rg) {
      long row = row0 + mi * 16 + rsub + rg;
#pragma unroll
      for (int ni = 0; ni < 4; ++ni) {
        int iv = (int)rintf((float)acc[mi][ni][rg] * osc);
        iv = iv > 127 ? 127 : (iv < -127 ? -127 : iv);
        base[row * (long)M_ + col00 + ni * 16] = (char)iv;
      }
    }
}

__global__ __launch_bounds__(256) void fatL4(
    const u16* __restrict__ qb, const u16* __restrict__ kb,
    const u16* __restrict__ vT, float* __restrict__ attn,
    const char* __restrict__ qi, const char* __restrict__ ki,
    char* __restrict__ sc8) {
  __shared__ __align__(16) char pool[49152];
  int p = blockIdx.x;
  if (p < 256) attn_body(pool, p, qb, kb, vT, attn);
  else sc8_body(pool, p - 256, qi, ki, sc8);
}

// ---------------- fused: approx top-64 (wave-local extraction) -> exact rescore ->
//                  top-32 -> mem attention -> combine ----------------
__global__ __launch_bounds__(256) void topk_tail_kernel(
    const char* __restrict__ scores, const float* __restrict__ qf,
    const float* __restrict__ mem, const float* __restrict__ attn,
    const float* __restrict__ gate, u16* __restrict__ comb) {
  int row = blockIdx.x, b = row >> 10;
  int tid = threadIdx.x, lane = tid & 63, w = tid >> 6;
  __shared__ unsigned candKey[256];
  __shared__ float qL[512];
  __shared__ float sL[NCAND_];
  __shared__ float sHh[NCAND_][8];
  __shared__ int cL[NCAND_];
  __shared__ int wIdx[TOPK_];
  __shared__ float eL[TOPK_][8];
  qL[tid] = qf[(size_t)row * C_ + tid];
  qL[256 + tid] = qf[(size_t)row * C_ + 256 + tid];
  const unsigned char* s = (const unsigned char*)scores + (size_t)row * M_;
  unsigned c[8];
#pragma unroll
  for (int i = 0; i < 8; ++i) c[i] = 0;
  for (int i2 = 0; i2 < 16; ++i2) {
    int base = i2 * 2048 + tid * 8;
    uint2 v = *(const uint2*)(s + base);
#pragma unroll
    for (int e = 0; e < 8; ++e) {
      unsigned byte = (e < 4) ? ((v.x >> (8 * e)) & 0xFF) : ((v.y >> (8 * (e - 4))) & 0xFF);
      unsigned key = byte ^ 0x80u;
      unsigned cmb = (key << 15) | (unsigned)(32767 - (base + e));
      if (cmb > c[7]) {
        c[7] = cmb;
#pragma unroll
        for (int ss = 7; ss > 0; --ss) {
          if (c[ss] > c[ss - 1]) { unsigned t = c[ss - 1]; c[ss - 1] = c[ss]; c[ss] = t; }
        }
      }
    }
  }
  for (int r = 0; r < 64; ++r) {
    unsigned bb = c[0];
#pragma unroll
    for (int m = 1; m < 64; m <<= 1) {
      unsigned o = __shfl_xor(bb, m);
      bb = (o > bb) ? o : bb;
    }
    if (lane == 0) candKey[w * 64 + r] = bb;
    if (c[0] == bb) {
#pragma unroll
      for (int ss = 0; ss < 7; ++ss) c[ss] = c[ss + 1];
      c[7] = 0;
    }
  }
  __syncthreads();
  {
    unsigned my = candKey[tid];
    int rank = 0;
    for (int j = 0; j < 256; ++j) rank += (candKey[j] > my);
    if (rank < NCAND_) cL[rank] = 32767 - (int)(my & 32767u);
  }
  __syncthreads();
#pragma unroll 4
  for (int i = 0; i < 16; ++i) {
    int cdx = w * 16 + i;
    const float* mrow = mem + ((size_t)(b * M_ + cL[cdx])) * 1024;
    f32x4 k0 = *(const f32x4*)(mrow + lane * 8);
    f32x4 k1 = *(const f32x4*)(mrow + lane * 8 + 4);
    float p = qL[lane*8+0]*k0[0] + qL[lane*8+1]*k0[1] + qL[lane*8+2]*k0[2] + qL[lane*8+3]*k0[3]
            + qL[lane*8+4]*k1[0] + qL[lane*8+5]*k1[1] + qL[lane*8+6]*k1[2] + qL[lane*8+7]*k1[3];
    p += __shfl_xor(p, 1); p += __shfl_xor(p, 2); p += __shfl_xor(p, 4);
    if ((lane & 7) == 0) sHh[cdx][lane >> 3] = p;
    float pf = p;
    pf += __shfl_xor(pf, 8); pf += __shfl_xor(pf, 16); pf += __shfl_xor(pf, 32);
    if (lane == 0) sL[cdx] = pf;
  }
  __syncthreads();
  if (tid < NCAND_) {
    float sv = sL[tid]; int id = cL[tid];
    int rank = 0;
#pragma unroll
    for (int j = 0; j < NCAND_; ++j) {
      float sj = sL[j];
      rank += (sj > sv) || (sj == sv && cL[j] < id);
    }
    if (rank < TOPK_) {
      wIdx[rank] = id;
#pragma unroll
      for (int h = 0; h < 8; ++h)
        eL[rank][h] = __expf(sHh[tid][h] * SCALE_);
    }
  }
  __syncthreads();
  int h2 = tid >> 5, dp = tid & 31;
  float num0 = 0.f, num1 = 0.f, den = 0.f;
#pragma unroll 8
  for (int k = 0; k < TOPK_; ++k) {
    float wgt = eL[k][h2];
    const float* vrow = mem + ((size_t)(b * M_ + wIdx[k])) * 1024 + 512;
    f32x2 vv = *(const f32x2*)(vrow + h2 * 64 + dp * 2);
    num0 += wgt * vv[0];
    num1 += wgt * vv[1];
    den += wgt;
  }
  float g = gate[h2];
  int c0 = h2 * 64 + dp * 2;
  float a0 = attn[(size_t)row * C_ + c0];
  float a1 = attn[(size_t)row * C_ + c0 + 1];
  u16 o0 = f2bf(g * (num0 / den) + (1.0f - g) * a0);
  u16 o1 = f2bf(g * (num1 / den) + (1.0f - g) * a1);
  *(unsigned*)(comb + (size_t)row * C_ + c0) = (unsigned)o0 | ((unsigned)o1 << 16);
}

extern "C" void kernel_launch(void* const* d_in, const int* in_sizes, int n_in,
                              void* d_out, int out_size, void* d_ws, size_t ws_size,
                              hipStream_t stream) {
  const float* x    = (const float*)d_in[0];
  const float* mem  = (const float*)d_in[1];
  const float* lnw  = (const float*)d_in[2];
  const float* lnb  = (const float*)d_in[3];
  const float* Wq   = (const float*)d_in[4];
  const float* bq   = (const float*)d_in[5];
  const float* Wk   = (const float*)d_in[6];
  const float* bk   = (const float*)d_in[7];
  const float* Wv   = (const float*)d_in[8];
  const float* bv   = (const float*)d_in[9];
  const float* Wo   = (const float*)d_in[10];
  const float* bo   = (const float*)d_in[11];
  const float* gate = (const float*)d_in[12];
  float* out   = (float*)d_out;
  float* kvout = out + (size_t)B_ * T_ * C_;

  size_t off = 0;
  auto alloc = [&](size_t bytes) {
    char* r = (char*)d_ws + off;
    off += (bytes + 255) & ~(size_t)255;
    return r;
  };
  u16*      WT   = (u16*)alloc(3ull * C_ * C_ * 2);
  char*     ki   = (char*)alloc((size_t)B_ * M_ * C_);
  u16*      xn   = (u16*)alloc((size_t)B_ * T_ * C_ * 2);
  float*    xnf  = (float*)alloc((size_t)B_ * T_ * C_ * 4);
  float*    qraw = (float*)alloc((size_t)B_ * T_ * C_ * 4);
  float*    kvraw= (float*)alloc(2ull * B_ * T_ * C_ * 4);
  float*    kraw = kvraw;
  float*    vraw = kvraw + (size_t)B_ * T_ * C_;
  float*    qf   = (float*)alloc((size_t)B_ * T_ * C_ * 4);
  u16*      qb   = (u16*)alloc((size_t)B_ * T_ * C_ * 2);
  u16*      kb   = (u16*)alloc((size_t)B_ * T_ * C_ * 2);
  char*     qi   = (char*)alloc((size_t)B_ * T_ * C_);
  u16*      vT   = (u16*)alloc((size_t)B_ * T_ * C_ * 2);
  float*    attn = (float*)alloc((size_t)B_ * T_ * C_ * 4);
  char*     sc8  = (char*)alloc((size_t)B_ * T_ * M_);
  u16*      comb = (u16*)alloc((size_t)B_ * T_ * C_ * 2);
  if (off > ws_size) return;

  wtrans_kernel<<<dim3(16, 16, 3), dim3(32, 8), 0, stream>>>(Wk, Wv, Wo, WT);
  prep_keys_kernel<<<8192, 256, 0, stream>>>(mem, ki);
  ln_kernel<<<512, 256, 0, stream>>>(x, lnw, lnb, xn, xnf);
  gemm_f32<<<dim3(32, 8), 256, 0, stream>>>(xnf, Wq, bq, qraw);
  gemm128<<<dim3(16, 4, 2), 256, 0, stream>>>(xn, 0, WT, (long)C_ * C_,
                                              kvraw, (long)B_ * T_ * C_, bk, bv, C_);
  postproc_kernel<<<512, 256, 0, stream>>>(qraw, kraw, vraw, qf, qb, kb, qi, kvout);
  vtrans_kernel<<<dim3(16, 8, 2), dim3(32, 8), 0, stream>>>(vraw, vT);
  fatL4<<<256 + 4096, 256, 0, stream>>>(qb, kb, vT, attn, qi, ki, sc8);
  topk_tail_kernel<<<2048, 256, 0, stream>>>(sc8, qf, mem, attn, gate, comb);
  gemm128<<<dim3(16, 4, 1), 256, 0, stream>>>(comb, 0, WT + 2 * C_ * C_, 0,
                                              out, 0, bo, nullptr, C_);
}

// Round 11
// 319.520 us; speedup vs baseline: 1.1130x; 1.0166x over previous
//
#include <hip/hip_runtime.h>
#include <hip/hip_bf16.h>

#define B_ 2
#define T_ 1024
#define H_ 8
#define D_ 64
#define C_ 512
#define M_ 32768
#define TOPK_ 32
#define NCAND_ 64
#define SCALE_ 0.125f
#define QSCALE_ 360.0f
#define KSCALE_ 24.0f
#define OSCALE_ 20.0f

typedef unsigned short u16;
typedef float    f32x2  __attribute__((ext_vector_type(2)));
typedef float    f32x4  __attribute__((ext_vector_type(4)));
typedef __bf16   bf16x8 __attribute__((ext_vector_type(8)));
typedef u16      u16x4  __attribute__((ext_vector_type(4)));
typedef int      i32x4  __attribute__((ext_vector_type(4)));
typedef unsigned char u8x4 __attribute__((ext_vector_type(4)));

__device__ __forceinline__ u16 f2bf(float f) {
  __hip_bfloat16 b = __float2bfloat16(f);
  u16 u; __builtin_memcpy(&u, &b, 2); return u;
}

__device__ __forceinline__ unsigned char q8(float v, float scale) {
  int iv = (int)rintf(v * scale);
  iv = iv > 127 ? 127 : (iv < -127 ? -127 : iv);
  return (unsigned char)(signed char)iv;
}

__device__ __forceinline__ void gl_lds16(const void* g, void* l) {
  __builtin_amdgcn_global_load_lds(
      (const __attribute__((address_space(1))) void*)g,
      (__attribute__((address_space(3))) void*)l, 16, 0, 0);
}

// ---------------- weight transpose: W[k][n] f32 -> WT[n][k] bf16 (Wk,Wv,Wo) ----------------
__global__ __launch_bounds__(256) void wtrans_kernel(
    const float* __restrict__ W0, const float* __restrict__ W1,
    const float* __restrict__ W2, u16* __restrict__ WT) {
  __shared__ u16 tl[32][33];
  int z = blockIdx.z;
  const float* W = (z == 0) ? W0 : (z == 1) ? W1 : W2;
  u16* dst = WT + (size_t)z * C_ * C_;
  int n0 = blockIdx.x * 32, k0 = blockIdx.y * 32;
  int tx = threadIdx.x, ty = threadIdx.y;
#pragma unroll
  for (int i = 0; i < 4; ++i) {
    int k = k0 + ty + i * 8;
    tl[ty + i * 8][tx] = f2bf(W[(size_t)k * C_ + n0 + tx]);
  }
  __syncthreads();
#pragma unroll
  for (int i = 0; i < 4; ++i) {
    int nn = ty + i * 8;
    dst[(size_t)(n0 + nn) * C_ + k0 + tx] = tl[tx][nn];
  }
}

// ---------------- keys f32 (strided in memory_kv) -> int8 [b][m][c], scale 24 ----------------
__global__ __launch_bounds__(256) void prep_keys_kernel(
    const float* __restrict__ mem, char* __restrict__ ki) {
  const int n4 = B_ * M_ * C_ / 4;
  for (int i = blockIdx.x * 256 + threadIdx.x; i < n4; i += gridDim.x * 256) {
    int row = i >> 7;
    int c4 = i & 127;
    f32x4 v = *(const f32x4*)(mem + ((size_t)row * 1024) + c4 * 4);
    u8x4 o;
    o[0] = q8(v[0], KSCALE_); o[1] = q8(v[1], KSCALE_);
    o[2] = q8(v[2], KSCALE_); o[3] = q8(v[3], KSCALE_);
    *(u8x4*)((unsigned char*)ki + (size_t)i * 4) = o;
  }
}

// ---------------- layernorm: x f32 -> xn bf16 + xnf f32 ----------------
__global__ __launch_bounds__(256) void ln_kernel(
    const float* __restrict__ x, const float* __restrict__ w,
    const float* __restrict__ bia, u16* __restrict__ xn, float* __restrict__ xnf) {
  int row = blockIdx.x * 4 + (threadIdx.x >> 6);
  int lane = threadIdx.x & 63;
  const float* xr = x + (size_t)row * C_;
  f32x4 v0 = *(const f32x4*)(xr + lane * 4);
  f32x4 v1 = *(const f32x4*)(xr + 256 + lane * 4);
  float s = v0[0] + v0[1] + v0[2] + v0[3] + v1[0] + v1[1] + v1[2] + v1[3];
  float q = v0[0]*v0[0]+v0[1]*v0[1]+v0[2]*v0[2]+v0[3]*v0[3]
          + v1[0]*v1[0]+v1[1]*v1[1]+v1[2]*v1[2]+v1[3]*v1[3];
#pragma unroll
  for (int m = 1; m < 64; m <<= 1) { s += __shfl_xor(s, m); q += __shfl_xor(q, m); }
  float mean = s * (1.0f / C_);
  float var  = q * (1.0f / C_) - mean * mean;
  float rs = rsqrtf(var + 1e-5f);
  u16x4 o0, o1;
  f32x4 f0, f1;
#pragma unroll
  for (int e = 0; e < 4; ++e) {
    int c = lane * 4 + e;
    f0[e] = (v0[e] - mean) * rs * w[c] + bia[c];
    o0[e] = f2bf(f0[e]);
    int c2 = 256 + lane * 4 + e;
    f1[e] = (v1[e] - mean) * rs * w[c2] + bia[c2];
    o1[e] = f2bf(f1[e]);
  }
  *(u16x4*)(xn + (size_t)row * C_ + lane * 4) = o0;
  *(u16x4*)(xn + (size_t)row * C_ + 256 + lane * 4) = o1;
  *(f32x4*)(xnf + (size_t)row * C_ + lane * 4) = f0;
  *(f32x4*)(xnf + (size_t)row * C_ + 256 + lane * 4) = f1;
}

// ---------------- exact f32 GEMM (for q): C = A(2048x512) * Bw(512x512) + bias ----------------
__global__ __launch_bounds__(256) void gemm_f32(
    const float* __restrict__ A, const float* __restrict__ Bw,
    const float* __restrict__ bias, float* __restrict__ Cout) {
  __shared__ float As[64][33];
  __shared__ float Bs[32][64];
  int tid = threadIdx.x;
  int tx = tid & 15, ty = tid >> 4;
  int r0 = blockIdx.x * 64, c0 = blockIdx.y * 64;
  f32x4 acc[4];
#pragma unroll
  for (int i = 0; i < 4; ++i) acc[i] = f32x4{0.f, 0.f, 0.f, 0.f};
  for (int kt = 0; kt < 16; ++kt) {
    int k0 = kt * 32;
#pragma unroll
    for (int i2 = 0; i2 < 2; ++i2) {
      int idx = i2 * 256 + tid;
      int arow = idx >> 3, ac = idx & 7;
      f32x4 av = *(const f32x4*)(A + (size_t)(r0 + arow) * 512 + k0 + ac * 4);
      As[arow][ac * 4 + 0] = av[0]; As[arow][ac * 4 + 1] = av[1];
      As[arow][ac * 4 + 2] = av[2]; As[arow][ac * 4 + 3] = av[3];
      int krow = idx >> 4, cc = idx & 15;
      f32x4 bv = *(const f32x4*)(Bw + (size_t)(k0 + krow) * 512 + c0 + cc * 4);
      *(f32x4*)(&Bs[krow][cc * 4]) = bv;
    }
    __syncthreads();
#pragma unroll
    for (int kk = 0; kk < 32; ++kk) {
      f32x4 bv = *(const f32x4*)(&Bs[kk][tx * 4]);
#pragma unroll
      for (int i = 0; i < 4; ++i) {
        float av = As[ty * 4 + i][kk];
        acc[i] += av * bv;
      }
    }
    __syncthreads();
  }
  f32x4 bb = *(const f32x4*)(bias + c0 + tx * 4);
#pragma unroll
  for (int i = 0; i < 4; ++i)
    *(f32x4*)(Cout + (size_t)(r0 + ty * 4 + i) * 512 + c0 + tx * 4) = acc[i] + bb;
}

// ---------------- generic 128x128 bf16 MFMA GEMM (f32 out + bias; z selects bias/bias2) -------
__global__ __launch_bounds__(256) void gemm128(
    const u16* __restrict__ A, long aBS,
    const u16* __restrict__ Bt, long bBS,
    float* __restrict__ Cf, long cBS,
    const float* __restrict__ bias, const float* __restrict__ bias2, int ldc) {
  __shared__ __align__(16) u16 As[128 * 64];
  __shared__ __align__(16) u16 Bs[128 * 64];
  const int tid = threadIdx.x;
  const int lane = tid & 63, w = tid >> 6;
  const int wm = w >> 1, wn = w & 1;
  const int z = blockIdx.z;
  const u16* Ab = A + (size_t)z * aBS + (size_t)blockIdx.x * 128 * 512;
  const u16* Bb = Bt + (size_t)z * bBS + (size_t)blockIdx.y * 128 * 512;

  f32x4 acc[4][4];
#pragma unroll
  for (int i = 0; i < 4; ++i)
#pragma unroll
    for (int j = 0; j < 4; ++j) acc[i][j] = f32x4{0.f, 0.f, 0.f, 0.f};

  for (int kt = 0; kt < 8; ++kt) {
    const u16* Akt = Ab + kt * 64;
    const u16* Bkt = Bb + kt * 64;
#pragma unroll
    for (int it = 0; it < 4; ++it) {
      int slot = it * 256 + tid;
      int rr = slot >> 3, ss = slot & 7;
      int q = ss ^ (rr & 7);
      gl_lds16(Akt + (size_t)rr * 512 + q * 8, (char*)As + slot * 16);
      gl_lds16(Bkt + (size_t)rr * 512 + q * 8, (char*)Bs + slot * 16);
    }
    __syncthreads();
#pragma unroll
    for (int kk = 0; kk < 2; ++kk) {
      bf16x8 av[4], bv[4];
#pragma unroll
      for (int i = 0; i < 4; ++i) {
        int blk = kk * 4 + (lane >> 4);
        int ra = wm * 64 + i * 16 + (lane & 15);
        av[i] = *(const bf16x8*)((const char*)As + ra * 128 + ((blk ^ (ra & 7)) << 4));
        int rb = wn * 64 + i * 16 + (lane & 15);
        bv[i] = *(const bf16x8*)((const char*)Bs + rb * 128 + ((blk ^ (rb & 7)) << 4));
      }
#pragma unroll
      for (int mi = 0; mi < 4; ++mi)
#pragma unroll
        for (int ni = 0; ni < 4; ++ni)
          acc[mi][ni] = __builtin_amdgcn_mfma_f32_16x16x32_bf16(av[mi], bv[ni], acc[mi][ni], 0, 0, 0);
    }
    __syncthreads();
  }
  const float* bi = (z == 1 && bias2) ? bias2 : bias;
  const long cbase = (long)z * cBS;
  const int rsub = (lane >> 4) * 4;
  const long row0 = (long)blockIdx.x * 128 + wm * 64;
  const int col00 = wn * 64 + (lane & 15) + (int)blockIdx.y * 128;
#pragma unroll
  for (int mi = 0; mi < 4; ++mi)
#pragma unroll
    for (int rg = 0; rg < 4; ++rg) {
      long row = row0 + mi * 16 + rsub + rg;
#pragma unroll
      for (int ni = 0; ni < 4; ++ni) {
        int col = col00 + ni * 16;
        float bb = bi ? bi[col] : 0.0f;
        Cf[cbase + row * (long)ldc + col] = acc[mi][ni][rg] + bb;
      }
    }
}

// ---------------- postprocess: l2norm q,k; emit outputs + q int8 ----------------
__global__ __launch_bounds__(256) void postproc_kernel(
    const float* __restrict__ qraw, const float* __restrict__ kraw,
    const float* __restrict__ vraw, float* __restrict__ qf,
    u16* __restrict__ qb, u16* __restrict__ kb, char* __restrict__ qi,
    float* __restrict__ kvout) {
  int row = blockIdx.x * 4 + (threadIdx.x >> 6);
  int lane = threadIdx.x & 63;
  size_t rb_ = (size_t)row * C_;
  f32x4 a0 = *(const f32x4*)(qraw + rb_ + lane * 4);
  f32x4 a1 = *(const f32x4*)(qraw + rb_ + 256 + lane * 4);
  float ss = a0[0]*a0[0]+a0[1]*a0[1]+a0[2]*a0[2]+a0[3]*a0[3]
           + a1[0]*a1[0]+a1[1]*a1[1]+a1[2]*a1[2]+a1[3]*a1[3];
#pragma unroll
  for (int m = 1; m < 64; m <<= 1) ss += __shfl_xor(ss, m);
  float rn = 1.0f / fmaxf(sqrtf(ss), 1e-12f);
  f32x4 q0 = a0 * rn, q1 = a1 * rn;
  *(f32x4*)(qf + rb_ + lane * 4) = q0;
  *(f32x4*)(qf + rb_ + 256 + lane * 4) = q1;
  u16x4 t0, t1;
#pragma unroll
  for (int e = 0; e < 4; ++e) { t0[e] = f2bf(q0[e]); t1[e] = f2bf(q1[e]); }
  *(u16x4*)(qb + rb_ + lane * 4) = t0;
  *(u16x4*)(qb + rb_ + 256 + lane * 4) = t1;
  u8x4 i0, i1;
#pragma unroll
  for (int e = 0; e < 4; ++e) { i0[e] = q8(q0[e], QSCALE_); i1[e] = q8(q1[e], QSCALE_); }
  *(u8x4*)((unsigned char*)qi + rb_ + lane * 4) = i0;
  *(u8x4*)((unsigned char*)qi + rb_ + 256 + lane * 4) = i1;
  f32x4 b0 = *(const f32x4*)(kraw + rb_ + lane * 4);
  f32x4 b1 = *(const f32x4*)(kraw + rb_ + 256 + lane * 4);
  float sk = b0[0]*b0[0]+b0[1]*b0[1]+b0[2]*b0[2]+b0[3]*b0[3]
           + b1[0]*b1[0]+b1[1]*b1[1]+b1[2]*b1[2]+b1[3]*b1[3];
#pragma unroll
  for (int m = 1; m < 64; m <<= 1) sk += __shfl_xor(sk, m);
  float rk = 1.0f / fmaxf(sqrtf(sk), 1e-12f);
  f32x4 k0 = b0 * rk, k1 = b1 * rk;
  size_t kvb = (size_t)row * (2 * C_);
  *(f32x4*)(kvout + kvb + lane * 4) = k0;
  *(f32x4*)(kvout + kvb + 256 + lane * 4) = k1;
#pragma unroll
  for (int e = 0; e < 4; ++e) { t0[e] = f2bf(k0[e]); t1[e] = f2bf(k1[e]); }
  *(u16x4*)(kb + rb_ + lane * 4) = t0;
  *(u16x4*)(kb + rb_ + 256 + lane * 4) = t1;
  f32x4 c0 = *(const f32x4*)(vraw + rb_ + lane * 4);
  f32x4 c1 = *(const f32x4*)(vraw + rb_ + 256 + lane * 4);
  *(f32x4*)(kvout + kvb + C_ + lane * 4) = c0;
  *(f32x4*)(kvout + kvb + C_ + 256 + lane * 4) = c1;
}

// ---------------- V transpose -> vT bf16 [b][h][d][t] ----------------
__global__ __launch_bounds__(256) void vtrans_kernel(
    const float* __restrict__ vraw, u16* __restrict__ vT) {
  __shared__ u16 tile[64][65];
  int tt = blockIdx.x, h = blockIdx.y, b = blockIdx.z;
  int tx = threadIdx.x, ty = threadIdx.y;
#pragma unroll
  for (int i = 0; i < 8; ++i) {
    int t = tt * 64 + ty + i * 8;
    const float* src = vraw + (size_t)(b * T_ + t) * C_ + h * 64;
    tile[ty + i * 8][tx] = f2bf(src[tx]);
    tile[ty + i * 8][tx + 32] = f2bf(src[tx + 32]);
  }
  __syncthreads();
#pragma unroll
  for (int i = 0; i < 8; ++i) {
    int d = ty + i * 8;
    u16* dst = vT + ((size_t)((b * H_ + h) * 64 + d)) * T_ + tt * 64;
    dst[tx] = tile[tx][d];
    dst[tx + 32] = tile[tx + 32][d];
  }
}

// ======== fused L4: causal flash attention (256 blocks) + int8 scores GEMM (4096 blocks) ======
// attn feeds only the bf16-tolerant output path; sc8 is integer-exact (i8 MFMA + one f32 mul
// + rintf on int < 2^24) — both provably robust to co-compilation codegen perturbation.

__device__ __forceinline__ void attn_body(char* pool, int p,
    const u16* __restrict__ qb, const u16* __restrict__ kb,
    const u16* __restrict__ vT, float* __restrict__ o) {
  u16* Ks = (u16*)pool;                 // [128*64]
  u16* Vs = (u16*)(pool + 16384);       // [64*128]
  char* PsBase = pool + 32768;          // [4][16*128] u16
  int tid = threadIdx.x, lane = tid & 63, w = tid >> 6;
  int it = p & 15, h = (p >> 4) & 7, b = p >> 7;
  char* PsW = PsBase + w * 4096;
  int t0 = it * 64;
  bf16x8 aq[2];
#pragma unroll
  for (int kk = 0; kk < 2; ++kk) {
    int row = t0 + w * 16 + (lane & 15);
    aq[kk] = *(const bf16x8*)(qb + (size_t)(b * T_ + row) * C_ + h * 64 + kk * 32 + (lane >> 4) * 8);
  }
  f32x4 accO[4];
  float denp[4];
#pragma unroll
  for (int j = 0; j < 4; ++j) { accO[j] = f32x4{0.f,0.f,0.f,0.f}; denp[j] = 0.f; }

  int ntiles = it / 2 + 1;
  for (int jt = 0; jt < ntiles; ++jt) {
    int j0 = jt * 128;
#pragma unroll
    for (int i2 = 0; i2 < 4; ++i2) {
      int slot = i2 * 256 + tid;
      int rr = slot >> 3, ssw = slot & 7;
      int q = ssw ^ (rr & 7);
      gl_lds16(kb + (size_t)(b * T_ + j0 + rr) * C_ + h * 64 + q * 8, (char*)Ks + slot * 16);
    }
#pragma unroll
    for (int i2 = 0; i2 < 4; ++i2) {
      int slot = i2 * 256 + tid;
      int rr = slot >> 4, ssw = slot & 15;
      int q = ssw ^ (rr & 15);
      gl_lds16(vT + ((size_t)((b * H_ + h) * 64 + rr)) * T_ + j0 + q * 8, (char*)Vs + slot * 16);
    }
    __syncthreads();
    f32x4 s[8];
#pragma unroll
    for (int ni = 0; ni < 8; ++ni) s[ni] = f32x4{0.f,0.f,0.f,0.f};
#pragma unroll
    for (int kk = 0; kk < 2; ++kk) {
      bf16x8 bk[8];
#pragma unroll
      for (int ni = 0; ni < 8; ++ni) {
        int rbi = ni * 16 + (lane & 15);
        int blk = kk * 4 + (lane >> 4);
        bk[ni] = *(const bf16x8*)((const char*)Ks + rbi * 128 + ((blk ^ (rbi & 7)) << 4));
      }
#pragma unroll
      for (int ni = 0; ni < 8; ++ni)
        s[ni] = __builtin_amdgcn_mfma_f32_16x16x32_bf16(aq[kk], bk[ni], s[ni], 0, 0, 0);
    }
#pragma unroll
    for (int ni = 0; ni < 8; ++ni)
#pragma unroll
      for (int rg = 0; rg < 4; ++rg) {
        int qrow = t0 + w * 16 + (lane >> 4) * 4 + rg;
        int kvcol = j0 + ni * 16 + (lane & 15);
        float sv = s[ni][rg] * SCALE_;
        float pp = (kvcol <= qrow) ? __expf(sv) : 0.0f;
        denp[rg] += pp;
        int qk = (lane >> 4) * 4 + rg;
        int kvl = ni * 16 + (lane & 15);
        int blk2 = kvl >> 3;
        *(u16*)(PsW + qk * 256 + ((blk2 ^ qk) << 4) + (kvl & 7) * 2) = f2bf(pp);
      }
#pragma unroll
    for (int kk2 = 0; kk2 < 4; ++kk2) {
      bf16x8 ap, bvv[4];
      int blk = kk2 * 4 + (lane >> 4);
      int rq = lane & 15;
      ap = *(const bf16x8*)(PsW + rq * 256 + ((blk ^ rq) << 4));
#pragma unroll
      for (int nd = 0; nd < 4; ++nd) {
        int rd = nd * 16 + (lane & 15);
        bvv[nd] = *(const bf16x8*)((const char*)Vs + rd * 256 + ((blk ^ (rd & 15)) << 4));
      }
#pragma unroll
      for (int nd = 0; nd < 4; ++nd)
        accO[nd] = __builtin_amdgcn_mfma_f32_16x16x32_bf16(ap, bvv[nd], accO[nd], 0, 0, 0);
    }
    __syncthreads();
  }
  float den[4];
#pragma unroll
  for (int rg = 0; rg < 4; ++rg) {
    float d = denp[rg];
    d += __shfl_xor(d, 1); d += __shfl_xor(d, 2);
    d += __shfl_xor(d, 4); d += __shfl_xor(d, 8);
    den[rg] = d;
  }
#pragma unroll
  for (int nd = 0; nd < 4; ++nd)
#pragma unroll
    for (int rg = 0; rg < 4; ++rg) {
      int row = t0 + w * 16 + (lane >> 4) * 4 + rg;
      int d = nd * 16 + (lane & 15);
      o[(size_t)(b * T_ + row) * C_ + h * 64 + d] = accO[nd][rg] / den[rg];
    }
}

// BK=128-byte i8 scores GEMM — byte-identical staging/swizzle geometry to the proven bf16
// gemm128 (16KB/operand, ss^(rr&7) swizzle, 2-way-free bank pattern, 32 MFMA per barrier-pair).
// Integer accumulation is associative-exact -> output bit-identical to the BK=64 version.
__device__ __forceinline__ void sc8_body(char* pool, int p,
    const char* __restrict__ A, const char* __restrict__ Bt, char* __restrict__ sc8) {
  char* As = pool;            // [128][128] bytes
  char* Bs = pool + 16384;    // [128][128] bytes
  const int tid = threadIdx.x;
  const int lane = tid & 63, w = tid >> 6;
  const int wm = w >> 1, wn = w & 1;
  const int z = p >> 11;
  const int q_ = p & 2047;
  const int r = (q_ >> 3) & 7;
  const int c = ((q_ >> 6) << 3) | (q_ & 7);
  const char* Ab = A + (size_t)z * T_ * C_ + (size_t)r * 128 * 512;
  const char* Bb = Bt + (size_t)z * M_ * C_ + (size_t)c * 128 * 512;

  i32x4 acc[4][4];
#pragma unroll
  for (int i = 0; i < 4; ++i)
#pragma unroll
    for (int j = 0; j < 4; ++j) acc[i][j] = i32x4{0, 0, 0, 0};

  for (int kt = 0; kt < 4; ++kt) {
    const char* Akt = Ab + kt * 128;
    const char* Bkt = Bb + kt * 128;
#pragma unroll
    for (int it = 0; it < 4; ++it) {
      int slot = it * 256 + tid;
      int rr = slot >> 3, ss = slot & 7;
      int ch = ss ^ (rr & 7);
      gl_lds16(Akt + (size_t)rr * 512 + ch * 16, As + slot * 16);
      gl_lds16(Bkt + (size_t)rr * 512 + ch * 16, Bs + slot * 16);
    }
    __syncthreads();
#pragma unroll
    for (int kk = 0; kk < 2; ++kk) {
      i32x4 av[4], bv[4];
#pragma unroll
      for (int i = 0; i < 4; ++i) {
        int blk = kk * 4 + (lane >> 4);
        int ra = wm * 64 + i * 16 + (lane & 15);
        av[i] = *(const i32x4*)(As + ra * 128 + ((blk ^ (ra & 7)) << 4));
        int rb = wn * 64 + i * 16 + (lane & 15);
        bv[i] = *(const i32x4*)(Bs + rb * 128 + ((blk ^ (rb & 7)) << 4));
      }
#pragma unroll
      for (int mi = 0; mi < 4; ++mi)
#pragma unroll
        for (int ni = 0; ni < 4; ++ni)
          acc[mi][ni] = __builtin_amdgcn_mfma_i32_16x16x64_i8(av[mi], bv[ni], acc[mi][ni], 0, 0, 0);
    }
    __syncthreads();
  }
  const int rsub = (lane >> 4) * 4;
  const long row0 = (long)r * 128 + wm * 64;
  const int col00 = c * 128 + wn * 64 + (lane & 15);
  char* base = sc8 + (size_t)z * T_ * M_;
  const float osc = OSCALE_ / (QSCALE_ * KSCALE_);
#pragma unroll
  for (int mi = 0; mi < 4; ++mi)
#pragma unroll
    for (int rg = 0; rg < 4; ++rg) {
      long row = row0 + mi * 16 + rsub + rg;
#pragma unroll
      for (int ni = 0; ni < 4; ++ni) {
        int iv = (int)rintf((float)acc[mi][ni][rg] * osc);
        iv = iv > 127 ? 127 : (iv < -127 ? -127 : iv);
        base[row * (long)M_ + col00 + ni * 16] = (char)iv;
      }
    }
}

__global__ __launch_bounds__(256) void fatL4(
    const u16* __restrict__ qb, const u16* __restrict__ kb,
    const u16* __restrict__ vT, float* __restrict__ attn,
    const char* __restrict__ qi, const char* __restrict__ ki,
    char* __restrict__ sc8) {
  __shared__ __align__(16) char pool[49152];
  int p = blockIdx.x;
  if (p < 256) attn_body(pool, p, qb, kb, vT, attn);
  else sc8_body(pool, p - 256, qi, ki, sc8);
}

// ---------------- fused: approx top-64 (wave-local extraction) -> exact rescore ->
//                  top-32 -> mem attention -> combine ----------------
__global__ __launch_bounds__(256) void topk_tail_kernel(
    const char* __restrict__ scores, const float* __restrict__ qf,
    const float* __restrict__ mem, const float* __restrict__ attn,
    const float* __restrict__ gate, u16* __restrict__ comb) {
  int row = blockIdx.x, b = row >> 10;
  int tid = threadIdx.x, lane = tid & 63, w = tid >> 6;
  __shared__ unsigned candKey[256];
  __shared__ float qL[512];
  __shared__ float sL[NCAND_];
  __shared__ float sHh[NCAND_][8];
  __shared__ int cL[NCAND_];
  __shared__ int wIdx[TOPK_];
  __shared__ float eL[TOPK_][8];
  qL[tid] = qf[(size_t)row * C_ + tid];
  qL[256 + tid] = qf[(size_t)row * C_ + 256 + tid];
  const unsigned char* s = (const unsigned char*)scores + (size_t)row * M_;
  unsigned c[8];
#pragma unroll
  for (int i = 0; i < 8; ++i) c[i] = 0;
  for (int i2 = 0; i2 < 16; ++i2) {
    int base = i2 * 2048 + tid * 8;
    uint2 v = *(const uint2*)(s + base);
#pragma unroll
    for (int e = 0; e < 8; ++e) {
      unsigned byte = (e < 4) ? ((v.x >> (8 * e)) & 0xFF) : ((v.y >> (8 * (e - 4))) & 0xFF);
      unsigned key = byte ^ 0x80u;
      unsigned cmb = (key << 15) | (unsigned)(32767 - (base + e));
      if (cmb > c[7]) {
        c[7] = cmb;
#pragma unroll
        for (int ss = 7; ss > 0; --ss) {
          if (c[ss] > c[ss - 1]) { unsigned t = c[ss - 1]; c[ss - 1] = c[ss]; c[ss] = t; }
        }
      }
    }
  }
  for (int r = 0; r < 64; ++r) {
    unsigned bb = c[0];
#pragma unroll
    for (int m = 1; m < 64; m <<= 1) {
      unsigned o = __shfl_xor(bb, m);
      bb = (o > bb) ? o : bb;
    }
    if (lane == 0) candKey[w * 64 + r] = bb;
    if (c[0] == bb) {
#pragma unroll
      for (int ss = 0; ss < 7; ++ss) c[ss] = c[ss + 1];
      c[7] = 0;
    }
  }
  __syncthreads();
  {
    unsigned my = candKey[tid];
    int rank = 0;
    for (int j = 0; j < 256; ++j) rank += (candKey[j] > my);
    if (rank < NCAND_) cL[rank] = 32767 - (int)(my & 32767u);
  }
  __syncthreads();
#pragma unroll 4
  for (int i = 0; i < 16; ++i) {
    int cdx = w * 16 + i;
    const float* mrow = mem + ((size_t)(b * M_ + cL[cdx])) * 1024;
    f32x4 k0 = *(const f32x4*)(mrow + lane * 8);
    f32x4 k1 = *(const f32x4*)(mrow + lane * 8 + 4);
    float p = qL[lane*8+0]*k0[0] + qL[lane*8+1]*k0[1] + qL[lane*8+2]*k0[2] + qL[lane*8+3]*k0[3]
            + qL[lane*8+4]*k1[0] + qL[lane*8+5]*k1[1] + qL[lane*8+6]*k1[2] + qL[lane*8+7]*k1[3];
    p += __shfl_xor(p, 1); p += __shfl_xor(p, 2); p += __shfl_xor(p, 4);
    if ((lane & 7) == 0) sHh[cdx][lane >> 3] = p;
    float pf = p;
    pf += __shfl_xor(pf, 8); pf += __shfl_xor(pf, 16); pf += __shfl_xor(pf, 32);
    if (lane == 0) sL[cdx] = pf;
  }
  __syncthreads();
  if (tid < NCAND_) {
    float sv = sL[tid]; int id = cL[tid];
    int rank = 0;
#pragma unroll
    for (int j = 0; j < NCAND_; ++j) {
      float sj = sL[j];
      rank += (sj > sv) || (sj == sv && cL[j] < id);
    }
    if (rank < TOPK_) {
      wIdx[rank] = id;
#pragma unroll
      for (int h = 0; h < 8; ++h)
        eL[rank][h] = __expf(sHh[tid][h] * SCALE_);
    }
  }
  __syncthreads();
  int h2 = tid >> 5, dp = tid & 31;
  float num0 = 0.f, num1 = 0.f, den = 0.f;
#pragma unroll 8
  for (int k = 0; k < TOPK_; ++k) {
    float wgt = eL[k][h2];
    const float* vrow = mem + ((size_t)(b * M_ + wIdx[k])) * 1024 + 512;
    f32x2 vv = *(const f32x2*)(vrow + h2 * 64 + dp * 2);
    num0 += wgt * vv[0];
    num1 += wgt * vv[1];
    den += wgt;
  }
  float g = gate[h2];
  int c0 = h2 * 64 + dp * 2;
  float a0 = attn[(size_t)row * C_ + c0];
  float a1 = attn[(size_t)row * C_ + c0 + 1];
  u16 o0 = f2bf(g * (num0 / den) + (1.0f - g) * a0);
  u16 o1 = f2bf(g * (num1 / den) + (1.0f - g) * a1);
  *(unsigned*)(comb + (size_t)row * C_ + c0) = (unsigned)o0 | ((unsigned)o1 << 16);
}

extern "C" void kernel_launch(void* const* d_in, const int* in_sizes, int n_in,
                              void* d_out, int out_size, void* d_ws, size_t ws_size,
                              hipStream_t stream) {
  const float* x    = (const float*)d_in[0];
  const float* mem  = (const float*)d_in[1];
  const float* lnw  = (const float*)d_in[2];
  const float* lnb  = (const float*)d_in[3];
  const float* Wq   = (const float*)d_in[4];
  const float* bq   = (const float*)d_in[5];
  const float* Wk   = (const float*)d_in[6];
  const float* bk   = (const float*)d_in[7];
  const float* Wv   = (const float*)d_in[8];
  const float* bv   = (const float*)d_in[9];
  const float* Wo   = (const float*)d_in[10];
  const float* bo   = (const float*)d_in[11];
  const float* gate = (const float*)d_in[12];
  float* out   = (float*)d_out;
  float* kvout = out + (size_t)B_ * T_ * C_;

  size_t off = 0;
  auto alloc = [&](size_t bytes) {
    char* r = (char*)d_ws + off;
    off += (bytes + 255) & ~(size_t)255;
    return r;
  };
  u16*      WT   = (u16*)alloc(3ull * C_ * C_ * 2);
  char*     ki   = (char*)alloc((size_t)B_ * M_ * C_);
  u16*      xn   = (u16*)alloc((size_t)B_ * T_ * C_ * 2);
  float*    xnf  = (float*)alloc((size_t)B_ * T_ * C_ * 4);
  float*    qraw = (float*)alloc((size_t)B_ * T_ * C_ * 4);
  float*    kvraw= (float*)alloc(2ull * B_ * T_ * C_ * 4);
  float*    kraw = kvraw;
  float*    vraw = kvraw + (size_t)B_ * T_ * C_;
  float*    qf   = (float*)alloc((size_t)B_ * T_ * C_ * 4);
  u16*      qb   = (u16*)alloc((size_t)B_ * T_ * C_ * 2);
  u16*      kb   = (u16*)alloc((size_t)B_ * T_ * C_ * 2);
  char*     qi   = (char*)alloc((size_t)B_ * T_ * C_);
  u16*      vT   = (u16*)alloc((size_t)B_ * T_ * C_ * 2);
  float*    attn = (float*)alloc((size_t)B_ * T_ * C_ * 4);
  char*     sc8  = (char*)alloc((size_t)B_ * T_ * M_);
  u16*      comb = (u16*)alloc((size_t)B_ * T_ * C_ * 2);
  if (off > ws_size) return;

  wtrans_kernel<<<dim3(16, 16, 3), dim3(32, 8), 0, stream>>>(Wk, Wv, Wo, WT);
  prep_keys_kernel<<<8192, 256, 0, stream>>>(mem, ki);
  ln_kernel<<<512, 256, 0, stream>>>(x, lnw, lnb, xn, xnf);
  gemm_f32<<<dim3(32, 8), 256, 0, stream>>>(xnf, Wq, bq, qraw);
  gemm128<<<dim3(16, 4, 2), 256, 0, stream>>>(xn, 0, WT, (long)C_ * C_,
                                              kvraw, (long)B_ * T_ * C_, bk, bv, C_);
  postproc_kernel<<<512, 256, 0, stream>>>(qraw, kraw, vraw, qf, qb, kb, qi, kvout);
  vtrans_kernel<<<dim3(16, 8, 2), dim3(32, 8), 0, stream>>>(vraw, vT);
  fatL4<<<256 + 4096, 256, 0, stream>>>(qb, kb, vT, attn, qi, ki, sc8);
  topk_tail_kernel<<<2048, 256, 0, stream>>>(sc8, qf, mem, attn, gate, comb);
  gemm128<<<dim3(16, 4, 1), 256, 0, stream>>>(comb, 0, WT + 2 * C_ * C_, 0,
                                              out, 0, bo, nullptr, C_);
}

// Round 12
// 290.687 us; speedup vs baseline: 1.2234x; 1.0992x over previous
//
#include <hip/hip_runtime.h>
#include <hip/hip_bf16.h>

#define B_ 2
#define T_ 1024
#define H_ 8
#define D_ 64
#define C_ 512
#define M_ 32768
#define TOPK_ 32
#define NCAND_ 64
#define SCALE_ 0.125f
#define QSCALE_ 360.0f
#define KSCALE_ 24.0f
#define OSCALE_ 20.0f

typedef unsigned short u16;
typedef float    f32x2  __attribute__((ext_vector_type(2)));
typedef float    f32x4  __attribute__((ext_vector_type(4)));
typedef __bf16   bf16x8 __attribute__((ext_vector_type(8)));
typedef u16      u16x4  __attribute__((ext_vector_type(4)));
typedef int      i32x4  __attribute__((ext_vector_type(4)));
typedef unsigned char u8x4 __attribute__((ext_vector_type(4)));

__device__ __forceinline__ u16 f2bf(float f) {
  __hip_bfloat16 b = __float2bfloat16(f);
  u16 u; __builtin_memcpy(&u, &b, 2); return u;
}

__device__ __forceinline__ unsigned char q8(float v, float scale) {
  int iv = (int)rintf(v * scale);
  iv = iv > 127 ? 127 : (iv < -127 ? -127 : iv);
  return (unsigned char)(signed char)iv;
}

__device__ __forceinline__ void gl_lds16(const void* g, void* l) {
  __builtin_amdgcn_global_load_lds(
      (const __attribute__((address_space(1))) void*)g,
      (__attribute__((address_space(3))) void*)l, 16, 0, 0);
}

// ======== fused prep: weight transpose (768 blocks) + key int8 quant (8192 blocks) ========
// Both bodies are single-IEEE-op-per-element (f2bf / mul+rintf+clamp) -> bit-exact under any
// codegen context (validated safe-merge rule).

__device__ __forceinline__ void wtrans_body(char* pool, int p,
    const float* __restrict__ W0, const float* __restrict__ W1,
    const float* __restrict__ W2, u16* __restrict__ WT) {
  u16 (*tl)[33] = (u16 (*)[33])pool;
  int z = p >> 8;
  int q = p & 255;
  const float* W = (z == 0) ? W0 : (z == 1) ? W1 : W2;
  u16* dst = WT + (size_t)z * C_ * C_;
  int n0 = (q & 15) * 32, k0 = (q >> 4) * 32;
  int tx = threadIdx.x & 31, ty = threadIdx.x >> 5;
#pragma unroll
  for (int i = 0; i < 4; ++i) {
    int k = k0 + ty + i * 8;
    tl[ty + i * 8][tx] = f2bf(W[(size_t)k * C_ + n0 + tx]);
  }
  __syncthreads();
#pragma unroll
  for (int i = 0; i < 4; ++i) {
    int nn = ty + i * 8;
    dst[(size_t)(n0 + nn) * C_ + k0 + tx] = tl[tx][nn];
  }
}

__device__ __forceinline__ void prep_keys_body(int bid,
    const float* __restrict__ mem, char* __restrict__ ki) {
  const int n4 = B_ * M_ * C_ / 4;
  for (int i = bid * 256 + (int)threadIdx.x; i < n4; i += 8192 * 256) {
    int row = i >> 7;
    int c4 = i & 127;
    f32x4 v = *(const f32x4*)(mem + ((size_t)row * 1024) + c4 * 4);
    u8x4 o;
    o[0] = q8(v[0], KSCALE_); o[1] = q8(v[1], KSCALE_);
    o[2] = q8(v[2], KSCALE_); o[3] = q8(v[3], KSCALE_);
    *(u8x4*)((unsigned char*)ki + (size_t)i * 4) = o;
  }
}

__global__ __launch_bounds__(256) void fatPrep(
    const float* __restrict__ W0, const float* __restrict__ W1,
    const float* __restrict__ W2, u16* __restrict__ WT,
    const float* __restrict__ mem, char* __restrict__ ki) {
  __shared__ __align__(16) char pool[2112];
  int p = blockIdx.x;
  if (p < 768) wtrans_body(pool, p, W0, W1, W2, WT);
  else prep_keys_body(p - 768, mem, ki);
}

// ---------------- layernorm: x f32 -> xn bf16 + xnf f32 ----------------
__global__ __launch_bounds__(256) void ln_kernel(
    const float* __restrict__ x, const float* __restrict__ w,
    const float* __restrict__ bia, u16* __restrict__ xn, float* __restrict__ xnf) {
  int row = blockIdx.x * 4 + (threadIdx.x >> 6);
  int lane = threadIdx.x & 63;
  const float* xr = x + (size_t)row * C_;
  f32x4 v0 = *(const f32x4*)(xr + lane * 4);
  f32x4 v1 = *(const f32x4*)(xr + 256 + lane * 4);
  float s = v0[0] + v0[1] + v0[2] + v0[3] + v1[0] + v1[1] + v1[2] + v1[3];
  float q = v0[0]*v0[0]+v0[1]*v0[1]+v0[2]*v0[2]+v0[3]*v0[3]
          + v1[0]*v1[0]+v1[1]*v1[1]+v1[2]*v1[2]+v1[3]*v1[3];
#pragma unroll
  for (int m = 1; m < 64; m <<= 1) { s += __shfl_xor(s, m); q += __shfl_xor(q, m); }
  float mean = s * (1.0f / C_);
  float var  = q * (1.0f / C_) - mean * mean;
  float rs = rsqrtf(var + 1e-5f);
  u16x4 o0, o1;
  f32x4 f0, f1;
#pragma unroll
  for (int e = 0; e < 4; ++e) {
    int c = lane * 4 + e;
    f0[e] = (v0[e] - mean) * rs * w[c] + bia[c];
    o0[e] = f2bf(f0[e]);
    int c2 = 256 + lane * 4 + e;
    f1[e] = (v1[e] - mean) * rs * w[c2] + bia[c2];
    o1[e] = f2bf(f1[e]);
  }
  *(u16x4*)(xn + (size_t)row * C_ + lane * 4) = o0;
  *(u16x4*)(xn + (size_t)row * C_ + 256 + lane * 4) = o1;
  *(f32x4*)(xnf + (size_t)row * C_ + lane * 4) = f0;
  *(f32x4*)(xnf + (size_t)row * C_ + 256 + lane * 4) = f1;
}

// ---------------- exact f32 GEMM (for q): C = A(2048x512) * Bw(512x512) + bias ----------------
// As stored transposed [k][row] (pad 68 -> aligned b128 reads, bank-spread). The FMA sequence
// per acc element (kt-major, kk 0..31, acc[i] += av*bv) is IDENTICAL to prior rounds ->
// qraw bit-identical; only the LDS access pattern changed (4 scalar reads -> 1 b128).
__global__ __launch_bounds__(256) void gemm_f32(
    const float* __restrict__ A, const float* __restrict__ Bw,
    const float* __restrict__ bias, float* __restrict__ Cout) {
  __shared__ float As_t[32][68];
  __shared__ float Bs[32][64];
  int tid = threadIdx.x;
  int tx = tid & 15, ty = tid >> 4;
  int r0 = blockIdx.x * 64, c0 = blockIdx.y * 64;
  f32x4 acc[4];
#pragma unroll
  for (int i = 0; i < 4; ++i) acc[i] = f32x4{0.f, 0.f, 0.f, 0.f};
  for (int kt = 0; kt < 16; ++kt) {
    int k0 = kt * 32;
#pragma unroll
    for (int i2 = 0; i2 < 2; ++i2) {
      int idx = i2 * 256 + tid;
      int arow = idx >> 3, ac = idx & 7;
      f32x4 av = *(const f32x4*)(A + (size_t)(r0 + arow) * 512 + k0 + ac * 4);
      As_t[ac * 4 + 0][arow] = av[0]; As_t[ac * 4 + 1][arow] = av[1];
      As_t[ac * 4 + 2][arow] = av[2]; As_t[ac * 4 + 3][arow] = av[3];
      int krow = idx >> 4, cc = idx & 15;
      f32x4 bv = *(const f32x4*)(Bw + (size_t)(k0 + krow) * 512 + c0 + cc * 4);
      *(f32x4*)(&Bs[krow][cc * 4]) = bv;
    }
    __syncthreads();
#pragma unroll
    for (int kk = 0; kk < 32; ++kk) {
      f32x4 bv = *(const f32x4*)(&Bs[kk][tx * 4]);
      f32x4 avv = *(const f32x4*)(&As_t[kk][ty * 4]);
#pragma unroll
      for (int i = 0; i < 4; ++i) {
        float av = avv[i];
        acc[i] += av * bv;
      }
    }
    __syncthreads();
  }
  f32x4 bb = *(const f32x4*)(bias + c0 + tx * 4);
#pragma unroll
  for (int i = 0; i < 4; ++i)
    *(f32x4*)(Cout + (size_t)(r0 + ty * 4 + i) * 512 + c0 + tx * 4) = acc[i] + bb;
}

// ---------------- generic 128x128 bf16 MFMA GEMM (f32 out + bias; z selects bias/bias2) -------
__global__ __launch_bounds__(256) void gemm128(
    const u16* __restrict__ A, long aBS,
    const u16* __restrict__ Bt, long bBS,
    float* __restrict__ Cf, long cBS,
    const float* __restrict__ bias, const float* __restrict__ bias2, int ldc) {
  __shared__ __align__(16) u16 As[128 * 64];
  __shared__ __align__(16) u16 Bs[128 * 64];
  const int tid = threadIdx.x;
  const int lane = tid & 63, w = tid >> 6;
  const int wm = w >> 1, wn = w & 1;
  const int z = blockIdx.z;
  const u16* Ab = A + (size_t)z * aBS + (size_t)blockIdx.x * 128 * 512;
  const u16* Bb = Bt + (size_t)z * bBS + (size_t)blockIdx.y * 128 * 512;

  f32x4 acc[4][4];
#pragma unroll
  for (int i = 0; i < 4; ++i)
#pragma unroll
    for (int j = 0; j < 4; ++j) acc[i][j] = f32x4{0.f, 0.f, 0.f, 0.f};

  for (int kt = 0; kt < 8; ++kt) {
    const u16* Akt = Ab + kt * 64;
    const u16* Bkt = Bb + kt * 64;
#pragma unroll
    for (int it = 0; it < 4; ++it) {
      int slot = it * 256 + tid;
      int rr = slot >> 3, ss = slot & 7;
      int q = ss ^ (rr & 7);
      gl_lds16(Akt + (size_t)rr * 512 + q * 8, (char*)As + slot * 16);
      gl_lds16(Bkt + (size_t)rr * 512 + q * 8, (char*)Bs + slot * 16);
    }
    __syncthreads();
#pragma unroll
    for (int kk = 0; kk < 2; ++kk) {
      bf16x8 av[4], bv[4];
#pragma unroll
      for (int i = 0; i < 4; ++i) {
        int blk = kk * 4 + (lane >> 4);
        int ra = wm * 64 + i * 16 + (lane & 15);
        av[i] = *(const bf16x8*)((const char*)As + ra * 128 + ((blk ^ (ra & 7)) << 4));
        int rb = wn * 64 + i * 16 + (lane & 15);
        bv[i] = *(const bf16x8*)((const char*)Bs + rb * 128 + ((blk ^ (rb & 7)) << 4));
      }
#pragma unroll
      for (int mi = 0; mi < 4; ++mi)
#pragma unroll
        for (int ni = 0; ni < 4; ++ni)
          acc[mi][ni] = __builtin_amdgcn_mfma_f32_16x16x32_bf16(av[mi], bv[ni], acc[mi][ni], 0, 0, 0);
    }
    __syncthreads();
  }
  const float* bi = (z == 1 && bias2) ? bias2 : bias;
  const long cbase = (long)z * cBS;
  const int rsub = (lane >> 4) * 4;
  const long row0 = (long)blockIdx.x * 128 + wm * 64;
  const int col00 = wn * 64 + (lane & 15) + (int)blockIdx.y * 128;
#pragma unroll
  for (int mi = 0; mi < 4; ++mi)
#pragma unroll
    for (int rg = 0; rg < 4; ++rg) {
      long row = row0 + mi * 16 + rsub + rg;
#pragma unroll
      for (int ni = 0; ni < 4; ++ni) {
        int col = col00 + ni * 16;
        float bb = bi ? bi[col] : 0.0f;
        Cf[cbase + row * (long)ldc + col] = acc[mi][ni][rg] + bb;
      }
    }
}

// ---------------- postprocess: l2norm q,k; emit outputs + q int8 ----------------
__global__ __launch_bounds__(256) void postproc_kernel(
    const float* __restrict__ qraw, const float* __restrict__ kraw,
    const float* __restrict__ vraw, float* __restrict__ qf,
    u16* __restrict__ qb, u16* __restrict__ kb, char* __restrict__ qi,
    float* __restrict__ kvout) {
  int row = blockIdx.x * 4 + (threadIdx.x >> 6);
  int lane = threadIdx.x & 63;
  size_t rb_ = (size_t)row * C_;
  f32x4 a0 = *(const f32x4*)(qraw + rb_ + lane * 4);
  f32x4 a1 = *(const f32x4*)(qraw + rb_ + 256 + lane * 4);
  float ss = a0[0]*a0[0]+a0[1]*a0[1]+a0[2]*a0[2]+a0[3]*a0[3]
           + a1[0]*a1[0]+a1[1]*a1[1]+a1[2]*a1[2]+a1[3]*a1[3];
#pragma unroll
  for (int m = 1; m < 64; m <<= 1) ss += __shfl_xor(ss, m);
  float rn = 1.0f / fmaxf(sqrtf(ss), 1e-12f);
  f32x4 q0 = a0 * rn, q1 = a1 * rn;
  *(f32x4*)(qf + rb_ + lane * 4) = q0;
  *(f32x4*)(qf + rb_ + 256 + lane * 4) = q1;
  u16x4 t0, t1;
#pragma unroll
  for (int e = 0; e < 4; ++e) { t0[e] = f2bf(q0[e]); t1[e] = f2bf(q1[e]); }
  *(u16x4*)(qb + rb_ + lane * 4) = t0;
  *(u16x4*)(qb + rb_ + 256 + lane * 4) = t1;
  u8x4 i0, i1;
#pragma unroll
  for (int e = 0; e < 4; ++e) { i0[e] = q8(q0[e], QSCALE_); i1[e] = q8(q1[e], QSCALE_); }
  *(u8x4*)((unsigned char*)qi + rb_ + lane * 4) = i0;
  *(u8x4*)((unsigned char*)qi + rb_ + 256 + lane * 4) = i1;
  f32x4 b0 = *(const f32x4*)(kraw + rb_ + lane * 4);
  f32x4 b1 = *(const f32x4*)(kraw + rb_ + 256 + lane * 4);
  float sk = b0[0]*b0[0]+b0[1]*b0[1]+b0[2]*b0[2]+b0[3]*b0[3]
           + b1[0]*b1[0]+b1[1]*b1[1]+b1[2]*b1[2]+b1[3]*b1[3];
#pragma unroll
  for (int m = 1; m < 64; m <<= 1) sk += __shfl_xor(sk, m);
  float rk = 1.0f / fmaxf(sqrtf(sk), 1e-12f);
  f32x4 k0 = b0 * rk, k1 = b1 * rk;
  size_t kvb = (size_t)row * (2 * C_);
  *(f32x4*)(kvout + kvb + lane * 4) = k0;
  *(f32x4*)(kvout + kvb + 256 + lane * 4) = k1;
#pragma unroll
  for (int e = 0; e < 4; ++e) { t0[e] = f2bf(k0[e]); t1[e] = f2bf(k1[e]); }
  *(u16x4*)(kb + rb_ + lane * 4) = t0;
  *(u16x4*)(kb + rb_ + 256 + lane * 4) = t1;
  f32x4 c0 = *(const f32x4*)(vraw + rb_ + lane * 4);
  f32x4 c1 = *(const f32x4*)(vraw + rb_ + 256 + lane * 4);
  *(f32x4*)(kvout + kvb + C_ + lane * 4) = c0;
  *(f32x4*)(kvout + kvb + C_ + 256 + lane * 4) = c1;
}

// ---------------- V transpose -> vT bf16 [b][h][d][t] ----------------
__global__ __launch_bounds__(256) void vtrans_kernel(
    const float* __restrict__ vraw, u16* __restrict__ vT) {
  __shared__ u16 tile[64][65];
  int tt = blockIdx.x, h = blockIdx.y, b = blockIdx.z;
  int tx = threadIdx.x, ty = threadIdx.y;
#pragma unroll
  for (int i = 0; i < 8; ++i) {
    int t = tt * 64 + ty + i * 8;
    const float* src = vraw + (size_t)(b * T_ + t) * C_ + h * 64;
    tile[ty + i * 8][tx] = f2bf(src[tx]);
    tile[ty + i * 8][tx + 32] = f2bf(src[tx + 32]);
  }
  __syncthreads();
#pragma unroll
  for (int i = 0; i < 8; ++i) {
    int d = ty + i * 8;
    u16* dst = vT + ((size_t)((b * H_ + h) * 64 + d)) * T_ + tt * 64;
    dst[tx] = tile[tx][d];
    dst[tx + 32] = tile[tx + 32][d];
  }
}

// ======== fused L4: causal flash attention (256 blocks) + int8 scores GEMM (4096 blocks) ======

__device__ __forceinline__ void attn_body(char* pool, int p,
    const u16* __restrict__ qb, const u16* __restrict__ kb,
    const u16* __restrict__ vT, float* __restrict__ o) {
  u16* Ks = (u16*)pool;                 // [128*64]
  u16* Vs = (u16*)(pool + 16384);       // [64*128]
  char* PsBase = pool + 32768;          // [4][16*128] u16
  int tid = threadIdx.x, lane = tid & 63, w = tid >> 6;
  int it = p & 15, h = (p >> 4) & 7, b = p >> 7;
  char* PsW = PsBase + w * 4096;
  int t0 = it * 64;
  bf16x8 aq[2];
#pragma unroll
  for (int kk = 0; kk < 2; ++kk) {
    int row = t0 + w * 16 + (lane & 15);
    aq[kk] = *(const bf16x8*)(qb + (size_t)(b * T_ + row) * C_ + h * 64 + kk * 32 + (lane >> 4) * 8);
  }
  f32x4 accO[4];
  float denp[4];
#pragma unroll
  for (int j = 0; j < 4; ++j) { accO[j] = f32x4{0.f,0.f,0.f,0.f}; denp[j] = 0.f; }

  int ntiles = it / 2 + 1;
  for (int jt = 0; jt < ntiles; ++jt) {
    int j0 = jt * 128;
#pragma unroll
    for (int i2 = 0; i2 < 4; ++i2) {
      int slot = i2 * 256 + tid;
      int rr = slot >> 3, ssw = slot & 7;
      int q = ssw ^ (rr & 7);
      gl_lds16(kb + (size_t)(b * T_ + j0 + rr) * C_ + h * 64 + q * 8, (char*)Ks + slot * 16);
    }
#pragma unroll
    for (int i2 = 0; i2 < 4; ++i2) {
      int slot = i2 * 256 + tid;
      int rr = slot >> 4, ssw = slot & 15;
      int q = ssw ^ (rr & 15);
      gl_lds16(vT + ((size_t)((b * H_ + h) * 64 + rr)) * T_ + j0 + q * 8, (char*)Vs + slot * 16);
    }
    __syncthreads();
    f32x4 s[8];
#pragma unroll
    for (int ni = 0; ni < 8; ++ni) s[ni] = f32x4{0.f,0.f,0.f,0.f};
#pragma unroll
    for (int kk = 0; kk < 2; ++kk) {
      bf16x8 bk[8];
#pragma unroll
      for (int ni = 0; ni < 8; ++ni) {
        int rbi = ni * 16 + (lane & 15);
        int blk = kk * 4 + (lane >> 4);
        bk[ni] = *(const bf16x8*)((const char*)Ks + rbi * 128 + ((blk ^ (rbi & 7)) << 4));
      }
#pragma unroll
      for (int ni = 0; ni < 8; ++ni)
        s[ni] = __builtin_amdgcn_mfma_f32_16x16x32_bf16(aq[kk], bk[ni], s[ni], 0, 0, 0);
    }
#pragma unroll
    for (int ni = 0; ni < 8; ++ni)
#pragma unroll
      for (int rg = 0; rg < 4; ++rg) {
        int qrow = t0 + w * 16 + (lane >> 4) * 4 + rg;
        int kvcol = j0 + ni * 16 + (lane & 15);
        float sv = s[ni][rg] * SCALE_;
        float pp = (kvcol <= qrow) ? __expf(sv) : 0.0f;
        denp[rg] += pp;
        int qk = (lane >> 4) * 4 + rg;
        int kvl = ni * 16 + (lane & 15);
        int blk2 = kvl >> 3;
        *(u16*)(PsW + qk * 256 + ((blk2 ^ qk) << 4) + (kvl & 7) * 2) = f2bf(pp);
      }
#pragma unroll
    for (int kk2 = 0; kk2 < 4; ++kk2) {
      bf16x8 ap, bvv[4];
      int blk = kk2 * 4 + (lane >> 4);
      int rq = lane & 15;
      ap = *(const bf16x8*)(PsW + rq * 256 + ((blk ^ rq) << 4));
#pragma unroll
      for (int nd = 0; nd < 4; ++nd) {
        int rd = nd * 16 + (lane & 15);
        bvv[nd] = *(const bf16x8*)((const char*)Vs + rd * 256 + ((blk ^ (rd & 15)) << 4));
      }
#pragma unroll
      for (int nd = 0; nd < 4; ++nd)
        accO[nd] = __builtin_amdgcn_mfma_f32_16x16x32_bf16(ap, bvv[nd], accO[nd], 0, 0, 0);
    }
    __syncthreads();
  }
  float den[4];
#pragma unroll
  for (int rg = 0; rg < 4; ++rg) {
    float d = denp[rg];
    d += __shfl_xor(d, 1); d += __shfl_xor(d, 2);
    d += __shfl_xor(d, 4); d += __shfl_xor(d, 8);
    den[rg] = d;
  }
#pragma unroll
  for (int nd = 0; nd < 4; ++nd)
#pragma unroll
    for (int rg = 0; rg < 4; ++rg) {
      int row = t0 + w * 16 + (lane >> 4) * 4 + rg;
      int d = nd * 16 + (lane & 15);
      o[(size_t)(b * T_ + row) * C_ + h * 64 + d] = accO[nd][rg] / den[rg];
    }
}

// BK=128-byte i8 scores GEMM — proven bf16 gemm128 staging/swizzle geometry; integer-exact.
__device__ __forceinline__ void sc8_body(char* pool, int p,
    const char* __restrict__ A, const char* __restrict__ Bt, char* __restrict__ sc8) {
  char* As = pool;            // [128][128] bytes
  char* Bs = pool + 16384;    // [128][128] bytes
  const int tid = threadIdx.x;
  const int lane = tid & 63, w = tid >> 6;
  const int wm = w >> 1, wn = w & 1;
  const int z = p >> 11;
  const int q_ = p & 2047;
  const int r = (q_ >> 3) & 7;
  const int c = ((q_ >> 6) << 3) | (q_ & 7);
  const char* Ab = A + (size_t)z * T_ * C_ + (size_t)r * 128 * 512;
  const char* Bb = Bt + (size_t)z * M_ * C_ + (size_t)c * 128 * 512;

  i32x4 acc[4][4];
#pragma unroll
  for (int i = 0; i < 4; ++i)
#pragma unroll
    for (int j = 0; j < 4; ++j) acc[i][j] = i32x4{0, 0, 0, 0};

  for (int kt = 0; kt < 4; ++kt) {
    const char* Akt = Ab + kt * 128;
    const char* Bkt = Bb + kt * 128;
#pragma unroll
    for (int it = 0; it < 4; ++it) {
      int slot = it * 256 + tid;
      int rr = slot >> 3, ss = slot & 7;
      int ch = ss ^ (rr & 7);
      gl_lds16(Akt + (size_t)rr * 512 + ch * 16, As + slot * 16);
      gl_lds16(Bkt + (size_t)rr * 512 + ch * 16, Bs + slot * 16);
    }
    __syncthreads();
#pragma unroll
    for (int kk = 0; kk < 2; ++kk) {
      i32x4 av[4], bv[4];
#pragma unroll
      for (int i = 0; i < 4; ++i) {
        int blk = kk * 4 + (lane >> 4);
        int ra = wm * 64 + i * 16 + (lane & 15);
        av[i] = *(const i32x4*)(As + ra * 128 + ((blk ^ (ra & 7)) << 4));
        int rb = wn * 64 + i * 16 + (lane & 15);
        bv[i] = *(const i32x4*)(Bs + rb * 128 + ((blk ^ (rb & 7)) << 4));
      }
#pragma unroll
      for (int mi = 0; mi < 4; ++mi)
#pragma unroll
        for (int ni = 0; ni < 4; ++ni)
          acc[mi][ni] = __builtin_amdgcn_mfma_i32_16x16x64_i8(av[mi], bv[ni], acc[mi][ni], 0, 0, 0);
    }
    __syncthreads();
  }
  const int rsub = (lane >> 4) * 4;
  const long row0 = (long)r * 128 + wm * 64;
  const int col00 = c * 128 + wn * 64 + (lane & 15);
  char* base = sc8 + (size_t)z * T_ * M_;
  const float osc = OSCALE_ / (QSCALE_ * KSCALE_);
#pragma unroll
  for (int mi = 0; mi < 4; ++mi)
#pragma unroll
    for (int rg = 0; rg < 4; ++rg) {
      long row = row0 + mi * 16 + rsub + rg;
#pragma unroll
      for (int ni = 0; ni < 4; ++ni) {
        int iv = (int)rintf((float)acc[mi][ni][rg] * osc);
        iv = iv > 127 ? 127 : (iv < -127 ? -127 : iv);
        base[row * (long)M_ + col00 + ni * 16] = (char)iv;
      }
    }
}

__global__ __launch_bounds__(256) void fatL4(
    const u16* __restrict__ qb, const u16* __restrict__ kb,
    const u16* __restrict__ vT, float* __restrict__ attn,
    const char* __restrict__ qi, const char* __restrict__ ki,
    char* __restrict__ sc8) {
  __shared__ __align__(16) char pool[49152];
  int p = blockIdx.x;
  if (p < 256) attn_body(pool, p, qb, kb, vT, attn);
  else sc8_body(pool, p - 256, qi, ki, sc8);
}

// ---------------- fused: approx top-64 (wave-local extraction) -> exact rescore ->
//                  top-32 -> mem attention -> combine ----------------
__global__ __launch_bounds__(256) void topk_tail_kernel(
    const char* __restrict__ scores, const float* __restrict__ qf,
    const float* __restrict__ mem, const float* __restrict__ attn,
    const float* __restrict__ gate, u16* __restrict__ comb) {
  int row = blockIdx.x, b = row >> 10;
  int tid = threadIdx.x, lane = tid & 63, w = tid >> 6;
  __shared__ unsigned candKey[256];
  __shared__ float qL[512];
  __shared__ float sL[NCAND_];
  __shared__ float sHh[NCAND_][8];
  __shared__ int cL[NCAND_];
  __shared__ int wIdx[TOPK_];
  __shared__ float eL[TOPK_][8];
  qL[tid] = qf[(size_t)row * C_ + tid];
  qL[256 + tid] = qf[(size_t)row * C_ + 256 + tid];
  const unsigned char* s = (const unsigned char*)scores + (size_t)row * M_;
  unsigned c[8];
#pragma unroll
  for (int i = 0; i < 8; ++i) c[i] = 0;
  for (int i2 = 0; i2 < 16; ++i2) {
    int base = i2 * 2048 + tid * 8;
    uint2 v = *(const uint2*)(s + base);
#pragma unroll
    for (int e = 0; e < 8; ++e) {
      unsigned byte = (e < 4) ? ((v.x >> (8 * e)) & 0xFF) : ((v.y >> (8 * (e - 4))) & 0xFF);
      unsigned key = byte ^ 0x80u;
      unsigned cmb = (key << 15) | (unsigned)(32767 - (base + e));
      if (cmb > c[7]) {
        c[7] = cmb;
#pragma unroll
        for (int ss = 7; ss > 0; --ss) {
          if (c[ss] > c[ss - 1]) { unsigned t = c[ss - 1]; c[ss - 1] = c[ss]; c[ss] = t; }
        }
      }
    }
  }
  for (int r = 0; r < 64; ++r) {
    unsigned bb = c[0];
#pragma unroll
    for (int m = 1; m < 64; m <<= 1) {
      unsigned o = __shfl_xor(bb, m);
      bb = (o > bb) ? o : bb;
    }
    if (lane == 0) candKey[w * 64 + r] = bb;
    if (c[0] == bb) {
#pragma unroll
      for (int ss = 0; ss < 7; ++ss) c[ss] = c[ss + 1];
      c[7] = 0;
    }
  }
  __syncthreads();
  {
    unsigned my = candKey[tid];
    int rank = 0;
    for (int j = 0; j < 256; ++j) rank += (candKey[j] > my);
    if (rank < NCAND_) cL[rank] = 32767 - (int)(my & 32767u);
  }
  __syncthreads();
#pragma unroll 4
  for (int i = 0; i < 16; ++i) {
    int cdx = w * 16 + i;
    const float* mrow = mem + ((size_t)(b * M_ + cL[cdx])) * 1024;
    f32x4 k0 = *(const f32x4*)(mrow + lane * 8);
    f32x4 k1 = *(const f32x4*)(mrow + lane * 8 + 4);
    float p = qL[lane*8+0]*k0[0] + qL[lane*8+1]*k0[1] + qL[lane*8+2]*k0[2] + qL[lane*8+3]*k0[3]
            + qL[lane*8+4]*k1[0] + qL[lane*8+5]*k1[1] + qL[lane*8+6]*k1[2] + qL[lane*8+7]*k1[3];
    p += __shfl_xor(p, 1); p += __shfl_xor(p, 2); p += __shfl_xor(p, 4);
    if ((lane & 7) == 0) sHh[cdx][lane >> 3] = p;
    float pf = p;
    pf += __shfl_xor(pf, 8); pf += __shfl_xor(pf, 16); pf += __shfl_xor(pf, 32);
    if (lane == 0) sL[cdx] = pf;
  }
  __syncthreads();
  if (tid < NCAND_) {
    float sv = sL[tid]; int id = cL[tid];
    int rank = 0;
#pragma unroll
    for (int j = 0; j < NCAND_; ++j) {
      float sj = sL[j];
      rank += (sj > sv) || (sj == sv && cL[j] < id);
    }
    if (rank < TOPK_) {
      wIdx[rank] = id;
#pragma unroll
      for (int h = 0; h < 8; ++h)
        eL[rank][h] = __expf(sHh[tid][h] * SCALE_);
    }
  }
  __syncthreads();
  int h2 = tid >> 5, dp = tid & 31;
  float num0 = 0.f, num1 = 0.f, den = 0.f;
#pragma unroll 8
  for (int k = 0; k < TOPK_; ++k) {
    float wgt = eL[k][h2];
    const float* vrow = mem + ((size_t)(b * M_ + wIdx[k])) * 1024 + 512;
    f32x2 vv = *(const f32x2*)(vrow + h2 * 64 + dp * 2);
    num0 += wgt * vv[0];
    num1 += wgt * vv[1];
    den += wgt;
  }
  float g = gate[h2];
  int c0 = h2 * 64 + dp * 2;
  float a0 = attn[(size_t)row * C_ + c0];
  float a1 = attn[(size_t)row * C_ + c0 + 1];
  u16 o0 = f2bf(g * (num0 / den) + (1.0f - g) * a0);
  u16 o1 = f2bf(g * (num1 / den) + (1.0f - g) * a1);
  *(unsigned*)(comb + (size_t)row * C_ + c0) = (unsigned)o0 | ((unsigned)o1 << 16);
}

extern "C" void kernel_launch(void* const* d_in, const int* in_sizes, int n_in,
                              void* d_out, int out_size, void* d_ws, size_t ws_size,
                              hipStream_t stream) {
  const float* x    = (const float*)d_in[0];
  const float* mem  = (const float*)d_in[1];
  const float* lnw  = (const float*)d_in[2];
  const float* lnb  = (const float*)d_in[3];
  const float* Wq   = (const float*)d_in[4];
  const float* bq   = (const float*)d_in[5];
  const float* Wk   = (const float*)d_in[6];
  const float* bk   = (const float*)d_in[7];
  const float* Wv   = (const float*)d_in[8];
  const float* bv   = (const float*)d_in[9];
  const float* Wo   = (const float*)d_in[10];
  const float* bo   = (const float*)d_in[11];
  const float* gate = (const float*)d_in[12];
  float* out   = (float*)d_out;
  float* kvout = out + (size_t)B_ * T_ * C_;

  size_t off = 0;
  auto alloc = [&](size_t bytes) {
    char* r = (char*)d_ws + off;
    off += (bytes + 255) & ~(size_t)255;
    return r;
  };
  u16*      WT   = (u16*)alloc(3ull * C_ * C_ * 2);
  char*     ki   = (char*)alloc((size_t)B_ * M_ * C_);
  u16*      xn   = (u16*)alloc((size_t)B_ * T_ * C_ * 2);
  float*    xnf  = (float*)alloc((size_t)B_ * T_ * C_ * 4);
  float*    qraw = (float*)alloc((size_t)B_ * T_ * C_ * 4);
  float*    kvraw= (float*)alloc(2ull * B_ * T_ * C_ * 4);
  float*    kraw = kvraw;
  float*    vraw = kvraw + (size_t)B_ * T_ * C_;
  float*    qf   = (float*)alloc((size_t)B_ * T_ * C_ * 4);
  u16*      qb   = (u16*)alloc((size_t)B_ * T_ * C_ * 2);
  u16*      kb   = (u16*)alloc((size_t)B_ * T_ * C_ * 2);
  char*     qi   = (char*)alloc((size_t)B_ * T_ * C_);
  u16*      vT   = (u16*)alloc((size_t)B_ * T_ * C_ * 2);
  float*    attn = (float*)alloc((size_t)B_ * T_ * C_ * 4);
  char*     sc8  = (char*)alloc((size_t)B_ * T_ * M_);
  u16*      comb = (u16*)alloc((size_t)B_ * T_ * C_ * 2);
  if (off > ws_size) return;

  fatPrep<<<768 + 8192, 256, 0, stream>>>(Wk, Wv, Wo, WT, mem, ki);
  ln_kernel<<<512, 256, 0, stream>>>(x, lnw, lnb, xn, xnf);
  gemm_f32<<<dim3(32, 8), 256, 0, stream>>>(xnf, Wq, bq, qraw);
  gemm128<<<dim3(16, 4, 2), 256, 0, stream>>>(xn, 0, WT, (long)C_ * C_,
                                              kvraw, (long)B_ * T_ * C_, bk, bv, C_);
  postproc_kernel<<<512, 256, 0, stream>>>(qraw, kraw, vraw, qf, qb, kb, qi, kvout);
  vtrans_kernel<<<dim3(16, 8, 2), dim3(32, 8), 0, stream>>>(vraw, vT);
  fatL4<<<256 + 4096, 256, 0, stream>>>(qb, kb, vT, attn, qi, ki, sc8);
  topk_tail_kernel<<<2048, 256, 0, stream>>>(sc8, qf, mem, attn, gate, comb);
  gemm128<<<dim3(16, 4, 1), 256, 0, stream>>>(comb, 0, WT + 2 * C_ * C_, 0,
                                              out, 0, bo, nullptr, C_);
}